// Round 1
// baseline (3860.344 us; speedup 1.0000x reference)
//
#include <hip/hip_runtime.h>
#include <hip/hip_bf16.h>
#include <math.h>

#define NB 32
#define CC 256
#define TT 64
#define VV 48
#define NTOK (NB*TT*VV)   // 98304
#define LNE 1e-5f

__device__ inline float bfbits2f(unsigned int bits){
    union{unsigned int u; float f;} c; c.u = bits<<16; return c.f;
}
__device__ inline unsigned short f2bf(float x){
    union{float f; unsigned int u;} c; c.f = x;
    unsigned int r = (c.u + 0x7fffu + ((c.u>>16)&1u)) >> 16;
    return (unsigned short)r;
}

// ---------------- weight prep: transposed layouts ----------------
__global__ void prep_weights(const float* gconv, const float* tcl0, const float* tcl1,
                             float* gct, float* wt0, float* wt1){
    int tid = blockIdx.x*blockDim.x + threadIdx.x;
    int stride = gridDim.x*blockDim.x;
    // gconvT[g][u][v] = gconv[g][v][u]
    for (int i = tid; i < 8*48*48; i += stride){
        int g = i/(48*48); int r = i%(48*48); int u = r/48; int v = r%48;
        gct[i] = gconv[(g*48+v)*48+u];
    }
    // wt[kh][i][o] = tcl[(o*192+i)*5+kh]
    for (int i = tid; i < 5*192*64; i += stride){
        int kh = i/(192*64); int r = i%(192*64); int ii = r/64; int o = r%64;
        wt0[i] = tcl0[(o*192+ii)*5+kh];
        wt1[i] = tcl1[(o*192+ii)*5+kh];
    }
}

// ---------------- LN1 stats over C for each token ----------------
__global__ __launch_bounds__(192) void ln1_stats(const float* __restrict__ x,
                                                 float* __restrict__ mean, float* __restrict__ rstd){
    int b = blockIdx.x / TT, t = blockIdx.x % TT;
    int v = threadIdx.x % 48, w = threadIdx.x / 48;   // w in 0..3
    const float* xb = x + ((size_t)b*CC)*TT*VV + t*VV;
    float s = 0.f, ss = 0.f;
    for (int c = w; c < CC; c += 4){
        float val = xb[(size_t)c*TT*VV + v];
        s += val; ss += val*val;
    }
    __shared__ float S[4][48], SS[4][48];
    S[w][v] = s; SS[w][v] = ss;
    __syncthreads();
    if (w == 0){
        float s0 = S[0][v]+S[1][v]+S[2][v]+S[3][v];
        float q0 = SS[0][v]+SS[1][v]+SS[2][v]+SS[3][v];
        float m = s0 * (1.0f/CC);
        float var = q0*(1.0f/CC) - m*m;
        int n = (b*TT+t)*VV + v;
        mean[n] = m; rstd[n] = rsqrtf(var + LNE);
    }
}

// ---------------- shared GEMM core: 48 tokens x 64 cols ----------------
// As row stride 260. thread: mq=tid%16 (4 cols), r=tid/16 (3 rows)
template<int M>
__device__ inline void gemm_core(const float* As, const float* W, int m0, int mq, int r,
                                 int K, float acc[3][4]){
    for (int k0 = 0; k0 < K; k0 += 4){
        float4 va = *(const float4*)(As + (r*3+0)*260 + k0);
        float4 vb = *(const float4*)(As + (r*3+1)*260 + k0);
        float4 vc = *(const float4*)(As + (r*3+2)*260 + k0);
        #pragma unroll
        for (int dk = 0; dk < 4; dk++){
            float4 w = *(const float4*)(W + (size_t)(k0+dk)*M + m0 + mq*4);
            float a0v = ((const float*)&va)[dk];
            float a1v = ((const float*)&vb)[dk];
            float a2v = ((const float*)&vc)[dk];
            acc[0][0]+=a0v*w.x; acc[0][1]+=a0v*w.y; acc[0][2]+=a0v*w.z; acc[0][3]+=a0v*w.w;
            acc[1][0]+=a1v*w.x; acc[1][1]+=a1v*w.y; acc[1][2]+=a1v*w.z; acc[1][3]+=a1v*w.w;
            acc[2][0]+=a2v*w.x; acc[2][1]+=a2v*w.y; acc[2][2]+=a2v*w.z; acc[2][3]+=a2v*w.w;
        }
    }
}

// ---------------- GEMM1: f = LN1(x^T) @ map_w + map_b ----------------
__global__ __launch_bounds__(256) void gemm_f(const float* __restrict__ x,
        const float* __restrict__ mean, const float* __restrict__ rstd,
        const float* __restrict__ g, const float* __restrict__ bb,
        const float* __restrict__ W, const float* __restrict__ bias, float* __restrict__ f){
    int bt = blockIdx.x; int b = bt/TT, t = bt%TT;
    int m0 = blockIdx.y*64;
    __shared__ float As[48*260];
    int nb = bt*VV;
    const float* xb = x + ((size_t)b*CC)*TT*VV + t*VV;
    for (int it = 0; it < 12; it++){
        int idx = it*256 + threadIdx.x;     // 0..3071 : q=v/4 (12), c (256)
        int q = idx % 12, c = idx / 12;
        float4 xv = *(const float4*)(xb + (size_t)c*TT*VV + q*4);
        float gg = g[c], bbv = bb[c];
        #pragma unroll
        for (int j = 0; j < 4; j++){
            int v = q*4+j;
            float val = (((const float*)&xv)[j] - mean[nb+v]) * rstd[nb+v];
            As[v*260 + c] = val*gg + bbv;
        }
    }
    __syncthreads();
    int mq = threadIdx.x % 16, r = threadIdx.x / 16;
    float acc[3][4] = {};
    gemm_core<256>(As, W, m0, mq, r, 256, acc);
    float4 b4 = *(const float4*)(bias + m0 + mq*4);
    #pragma unroll
    for (int j = 0; j < 3; j++){
        int v = r*3+j;
        float4 o;
        o.x = acc[j][0]+b4.x; o.y = acc[j][1]+b4.y; o.z = acc[j][2]+b4.z; o.w = acc[j][3]+b4.w;
        *(float4*)(f + (size_t)(nb+v)*256 + m0 + mq*4) = o;
    }
}

// ---------------- fused attention: qkv GEMM + 16x16 attn + out proj ----------------
__global__ __launch_bounds__(192) void attn_fused(const float* __restrict__ f, int coff,
        const float* __restrict__ qkvw, const float* __restrict__ qkvb,
        const float* __restrict__ pw, const float* __restrict__ pb, float* __restrict__ aout){
    int bt = blockIdx.x; int nb = bt*VV;
    __shared__ float X[48*68];     // input slice, later reused as attention output
    __shared__ float Q[48*196];    // qkv (48 x 192)
    int tid = threadIdx.x;
    for (int idx = tid; idx < 768; idx += 192){
        int v = idx/16, c4 = idx%16;
        float4 xv = *(const float4*)(f + (size_t)(nb+v)*256 + coff + c4*4);
        *(float4*)(&X[v*68 + c4*4]) = xv;
    }
    __syncthreads();
    // qkv: thread j computes column j over all 48 rows
    {
        int j = tid;
        float acc[48];
        #pragma unroll
        for (int v = 0; v < 48; v++) acc[v] = 0.f;
        for (int c0 = 0; c0 < 64; c0 += 4){
            float w0 = qkvw[(c0+0)*192+j], w1 = qkvw[(c0+1)*192+j];
            float w2 = qkvw[(c0+2)*192+j], w3 = qkvw[(c0+3)*192+j];
            #pragma unroll
            for (int v = 0; v < 48; v++){
                float4 xv = *(const float4*)(&X[v*68 + c0]);
                acc[v] += xv.x*w0 + xv.y*w1 + xv.z*w2 + xv.w*w3;
            }
        }
        float bj = qkvb[j];
        #pragma unroll
        for (int v = 0; v < 48; v++) Q[v*196 + j] = acc[v] + bj;
    }
    __syncthreads();
    // attention: 12 (g,h) heads x 16 rows = 192 threads
    {
        int u = tid % 16, gh = tid / 16, g = gh >> 2, h = gh & 3;
        int ru = g*16+u;
        float qreg[16];
        #pragma unroll
        for (int d = 0; d < 16; d++) qreg[d] = Q[ru*196 + h*16 + d];
        float sc[16]; float mx = -1e30f;
        #pragma unroll
        for (int w = 0; w < 16; w++){
            float s = 0.f;
            #pragma unroll
            for (int d = 0; d < 16; d++) s += qreg[d]*Q[(g*16+w)*196 + 64 + h*16 + d];
            s *= 0.5f; sc[w] = s; mx = fmaxf(mx, s);
        }
        float sum = 0.f;
        #pragma unroll
        for (int w = 0; w < 16; w++){ sc[w] = expf(sc[w]-mx); sum += sc[w]; }
        float inv = 1.0f/sum;
        float ol[16];
        #pragma unroll
        for (int d = 0; d < 16; d++){
            float o = 0.f;
            #pragma unroll
            for (int w = 0; w < 16; w++) o += sc[w]*Q[(g*16+w)*196 + 128 + h*16 + d];
            ol[d] = o*inv;
        }
        #pragma unroll
        for (int d = 0; d < 16; d++) X[ru*68 + h*16 + d] = ol[d];
    }
    __syncthreads();
    // out projection
    {
        int j = tid;
        float acc[48];
        #pragma unroll
        for (int v = 0; v < 48; v++) acc[v] = 0.f;
        for (int c0 = 0; c0 < 64; c0 += 4){
            float w0 = pw[(c0+0)*192+j], w1 = pw[(c0+1)*192+j];
            float w2 = pw[(c0+2)*192+j], w3 = pw[(c0+3)*192+j];
            #pragma unroll
            for (int v = 0; v < 48; v++){
                float4 xv = *(const float4*)(&X[v*68 + c0]);
                acc[v] += xv.x*w0 + xv.y*w1 + xv.z*w2 + xv.w*w3;
            }
        }
        float bj = pb[j];
        #pragma unroll
        for (int v = 0; v < 48; v++) aout[(size_t)(nb+v)*192 + j] = acc[v] + bj;
    }
}

// ---------------- y0: grouped V-mix, in-place on f cols 0..63 ----------------
__global__ __launch_bounds__(256) void y0_kernel(float* __restrict__ f, const float* __restrict__ gct){
    int bt = blockIdx.x; int nb = bt*VV;
    __shared__ float X[48*68];
    for (int it = 0; it < 3; it++){
        int idx = it*256 + threadIdx.x;
        int v = idx/16, c4 = idx%16;
        float4 xv = *(const float4*)(f + (size_t)(nb+v)*256 + c4*4);
        *(float4*)(&X[v*68 + c4*4]) = xv;
    }
    __syncthreads();
    int c = threadIdx.x % 64, vv = threadIdx.x / 64;
    int g = c >> 3;
    float acc[12] = {};
    for (int u = 0; u < 48; u++){
        float xv = X[u*68 + c];
        const float* gr = gct + (size_t)(g*48+u)*48 + vv*12;
        float4 g0 = *(const float4*)(gr);
        float4 g1 = *(const float4*)(gr+4);
        float4 g2 = *(const float4*)(gr+8);
        acc[0]+=xv*g0.x; acc[1]+=xv*g0.y; acc[2]+=xv*g0.z;  acc[3]+=xv*g0.w;
        acc[4]+=xv*g1.x; acc[5]+=xv*g1.y; acc[6]+=xv*g1.z;  acc[7]+=xv*g1.w;
        acc[8]+=xv*g2.x; acc[9]+=xv*g2.y; acc[10]+=xv*g2.z; acc[11]+=xv*g2.w;
    }
    #pragma unroll
    for (int j = 0; j < 12; j++)
        f[(size_t)(nb + vv*12 + j)*256 + c] = acc[j];
}

// ---------------- y1: grouped temporal conv (k=7), writes y1buf (N x 64) ----------------
__global__ __launch_bounds__(256) void y1_kernel(const float* __restrict__ f,
        const float* __restrict__ tw, const float* __restrict__ tb, float* __restrict__ y1buf){
    int bt = blockIdx.x; int b = bt/TT, t = bt%TT;
    int o = threadIdx.x % 64, vv = threadIdx.x / 64;
    int g = o >> 3;
    float bv = tb[o];
    float acc[12];
    #pragma unroll
    for (int j = 0; j < 12; j++) acc[j] = bv;
    for (int kh = 0; kh < 7; kh++){
        int tt = t + kh - 3;
        if (tt < 0 || tt >= TT) continue;
        float wk[8];
        #pragma unroll
        for (int ci = 0; ci < 8; ci++) wk[ci] = tw[(o*8+ci)*7 + kh];
        int nb2 = (b*TT+tt)*VV;
        #pragma unroll
        for (int j = 0; j < 12; j++){
            const float* fr = f + (size_t)(nb2 + vv*12 + j)*256 + 64 + g*8;
            float4 f0 = *(const float4*)fr;
            float4 f1 = *(const float4*)(fr+4);
            acc[j] += f0.x*wk[0]+f0.y*wk[1]+f0.z*wk[2]+f0.w*wk[3]
                    + f1.x*wk[4]+f1.y*wk[5]+f1.z*wk[6]+f1.w*wk[7];
        }
    }
    int nb = bt*VV;
    #pragma unroll
    for (int j = 0; j < 12; j++)
        y1buf[(size_t)(nb + vv*12 + j)*64 + o] = acc[j];
}

// ---------------- y2/y3: causal temporal conv k=5 over 192ch, writes f cols outoff.. ----------------
__global__ __launch_bounds__(256) void tcl_kernel(const float* __restrict__ a,
        const float* __restrict__ wt, const float* __restrict__ tb,
        float* __restrict__ f, int outoff){
    int bt = blockIdx.x; int b = bt/TT, t = bt%TT;
    __shared__ float As[48*196];
    int o = threadIdx.x % 64, vv = threadIdx.x / 64;
    float bvv = tb[o];
    float acc[12];
    #pragma unroll
    for (int j = 0; j < 12; j++) acc[j] = bvv;
    for (int kh = 0; kh < 5; kh++){
        int tt = t + kh - 4;
        if (tt < 0) continue;
        __syncthreads();
        int nb2 = (b*TT+tt)*VV;
        for (int it = 0; it < 9; it++){
            int idx = it*256 + threadIdx.x;       // 48*48 float4
            int v = idx/48, c4 = idx%48;
            *(float4*)(&As[v*196 + c4*4]) = *(const float4*)(a + (size_t)(nb2+v)*192 + c4*4);
        }
        __syncthreads();
        const float* wk = wt + kh*192*64;
        for (int i0 = 0; i0 < 192; i0 += 4){
            float w0 = wk[(i0+0)*64+o];
            float w1 = wk[(i0+1)*64+o];
            float w2 = wk[(i0+2)*64+o];
            float w3 = wk[(i0+3)*64+o];
            #pragma unroll
            for (int j = 0; j < 12; j++){
                float4 av = *(const float4*)(&As[(vv*12+j)*196 + i0]);
                acc[j] += av.x*w0 + av.y*w1 + av.z*w2 + av.w*w3;
            }
        }
    }
    int nb = bt*VV;
    #pragma unroll
    for (int j = 0; j < 12; j++)
        f[(size_t)(nb + vv*12 + j)*256 + outoff + o] = acc[j];
}

// ---------------- GEMM6: out = skip + y @ proj_w + proj_b ----------------
__global__ __launch_bounds__(256) void gemm_out(const float* __restrict__ f,
        const float* __restrict__ y1buf, const float* __restrict__ x,
        const float* __restrict__ W, const float* __restrict__ bias, float* __restrict__ outt){
    int bt = blockIdx.x; int b = bt/TT, t = bt%TT; int m0 = blockIdx.y*64;
    __shared__ float As[48*260];
    __shared__ float Sk[48*68];
    int nb = bt*VV;
    for (int it = 0; it < 12; it++){
        int idx = it*256 + threadIdx.x;       // 48 x 64 float4
        int v = idx/64, c4 = idx%64;
        float4 val;
        if (c4 >= 16 && c4 < 32) val = *(const float4*)(y1buf + (size_t)(nb+v)*64 + (c4-16)*4);
        else                     val = *(const float4*)(f + (size_t)(nb+v)*256 + c4*4);
        *(float4*)(&As[v*260 + c4*4]) = val;
    }
    const float* xb = x + ((size_t)b*CC + m0)*TT*VV + t*VV;
    for (int it = 0; it < 3; it++){
        int idx = it*256 + threadIdx.x;       // 768: 64 rows x 12 float4
        int cR = idx/12, q = idx%12;
        float4 xv = *(const float4*)(xb + (size_t)cR*TT*VV + q*4);
        Sk[(q*4+0)*68 + cR] = xv.x;
        Sk[(q*4+1)*68 + cR] = xv.y;
        Sk[(q*4+2)*68 + cR] = xv.z;
        Sk[(q*4+3)*68 + cR] = xv.w;
    }
    __syncthreads();
    int mq = threadIdx.x % 16, r = threadIdx.x / 16;
    float acc[3][4] = {};
    gemm_core<256>(As, W, m0, mq, r, 256, acc);
    float4 b4 = *(const float4*)(bias + m0 + mq*4);
    #pragma unroll
    for (int j = 0; j < 3; j++){
        int v = r*3+j;
        float4 o;
        o.x = acc[j][0]+b4.x+Sk[v*68 + mq*4+0];
        o.y = acc[j][1]+b4.y+Sk[v*68 + mq*4+1];
        o.z = acc[j][2]+b4.z+Sk[v*68 + mq*4+2];
        o.w = acc[j][3]+b4.w+Sk[v*68 + mq*4+3];
        *(float4*)(outt + (size_t)(nb+v)*256 + m0 + mq*4) = o;
    }
}

// ---------------- LN2 stats (token-major rows) ----------------
__global__ __launch_bounds__(256) void ln2_stats(const float* __restrict__ outt,
        float* __restrict__ mean, float* __restrict__ rstd){
    int n = blockIdx.x*4 + (threadIdx.x >> 6);
    int lane = threadIdx.x & 63;
    float4 v = *(const float4*)(outt + (size_t)n*256 + lane*4);
    float s = v.x+v.y+v.z+v.w;
    float ss = v.x*v.x+v.y*v.y+v.z*v.z+v.w*v.w;
    for (int off = 32; off > 0; off >>= 1){
        s += __shfl_down(s, off);
        ss += __shfl_down(ss, off);
    }
    if (lane == 0){
        float m = s*(1.0f/CC);
        float var = ss*(1.0f/CC) - m*m;
        mean[n] = m; rstd[n] = rsqrtf(var + LNE);
    }
}

// ---------------- GEMM7: h = gelu(LN2(out) @ mlp_w1 + b1), bf16 out ----------------
__global__ __launch_bounds__(256) void gemm_h(const float* __restrict__ outt,
        const float* __restrict__ mean, const float* __restrict__ rstd,
        const float* __restrict__ g, const float* __restrict__ bb,
        const float* __restrict__ W, const float* __restrict__ bias,
        unsigned short* __restrict__ h){
    int bt = blockIdx.x; int m0 = blockIdx.y*64;
    __shared__ float As[48*260];
    int nb = bt*VV;
    for (int it = 0; it < 12; it++){
        int idx = it*256 + threadIdx.x;
        int v = idx/64, c4 = idx%64;
        int n = nb+v;
        float4 xv = *(const float4*)(outt + (size_t)n*256 + c4*4);
        float m = mean[n], rs = rstd[n];
        float4 g4 = *(const float4*)(g + c4*4);
        float4 b4 = *(const float4*)(bb + c4*4);
        As[v*260 + c4*4+0] = (xv.x-m)*rs*g4.x + b4.x;
        As[v*260 + c4*4+1] = (xv.y-m)*rs*g4.y + b4.y;
        As[v*260 + c4*4+2] = (xv.z-m)*rs*g4.z + b4.z;
        As[v*260 + c4*4+3] = (xv.w-m)*rs*g4.w + b4.w;
    }
    __syncthreads();
    int mq = threadIdx.x % 16, r = threadIdx.x / 16;
    float acc[3][4] = {};
    gemm_core<1024>(As, W, m0, mq, r, 256, acc);
    float4 b4 = *(const float4*)(bias + m0 + mq*4);
    #pragma unroll
    for (int j = 0; j < 3; j++){
        int v = r*3+j; int n = nb+v;
        ushort4 u;
        {
            float t0 = acc[j][0]+b4.x; t0 = 0.5f*t0*(1.0f+erff(t0*0.70710678118f)); u.x = f2bf(t0);
            float t1 = acc[j][1]+b4.y; t1 = 0.5f*t1*(1.0f+erff(t1*0.70710678118f)); u.y = f2bf(t1);
            float t2 = acc[j][2]+b4.z; t2 = 0.5f*t2*(1.0f+erff(t2*0.70710678118f)); u.z = f2bf(t2);
            float t3 = acc[j][3]+b4.w; t3 = 0.5f*t3*(1.0f+erff(t3*0.70710678118f)); u.w = f2bf(t3);
        }
        *(ushort4*)(h + (size_t)n*1024 + m0 + mq*4) = u;
    }
}

// ---------------- GEMM8: out2 = out + h @ mlp_w2 + b2, transposed store ----------------
__global__ __launch_bounds__(256) void gemm_final(const unsigned short* __restrict__ h,
        const float* __restrict__ outt, const float* __restrict__ W,
        const float* __restrict__ bias, float* __restrict__ dout){
    int bt = blockIdx.x; int b = bt/TT, t = bt%TT; int m0 = blockIdx.y*64;
    __shared__ float As[48*260];
    __shared__ float Tt[64*49];
    int tid = threadIdx.x;
    int mq = tid % 16, r = tid / 16;
    float acc[3][4] = {};
    int nb = bt*VV;
    for (int k0 = 0; k0 < 1024; k0 += 256){
        __syncthreads();
        for (int it = 0; it < 6; it++){
            int idx = it*256 + tid;           // 1536 = 48 x 32 (8 bf16 each)
            int v = idx/32, q = idx%32;
            uint4 u = *(const uint4*)(h + (size_t)(nb+v)*1024 + k0 + q*8);
            float* dst = &As[v*260 + q*8];
            dst[0]=bfbits2f(u.x&0xffffu); dst[1]=bfbits2f(u.x>>16);
            dst[2]=bfbits2f(u.y&0xffffu); dst[3]=bfbits2f(u.y>>16);
            dst[4]=bfbits2f(u.z&0xffffu); dst[5]=bfbits2f(u.z>>16);
            dst[6]=bfbits2f(u.w&0xffffu); dst[7]=bfbits2f(u.w>>16);
        }
        __syncthreads();
        gemm_core<256>(As, W + (size_t)k0*256, m0, mq, r, 256, acc);
    }
    float4 b4 = *(const float4*)(bias + m0 + mq*4);
    #pragma unroll
    for (int j = 0; j < 3; j++){
        int v = r*3+j; int n = nb+v;
        float4 res = *(const float4*)(outt + (size_t)n*256 + m0 + mq*4);
        Tt[(mq*4+0)*49 + v] = acc[j][0]+b4.x+res.x;
        Tt[(mq*4+1)*49 + v] = acc[j][1]+b4.y+res.y;
        Tt[(mq*4+2)*49 + v] = acc[j][2]+b4.z+res.z;
        Tt[(mq*4+3)*49 + v] = acc[j][3]+b4.w+res.w;
    }
    __syncthreads();
    int mrow = tid/4, vs = (tid%4)*12;
    float* dp = dout + ((size_t)(b*CC + m0 + mrow)*TT + t)*VV + vs;
    const float* sp = &Tt[mrow*49 + vs];
    #pragma unroll
    for (int s = 0; s < 12; s++) dp[s] = sp[s];
}

extern "C" void kernel_launch(void* const* d_in, const int* in_sizes, int n_in,
                              void* d_out, int out_size, void* d_ws, size_t ws_size,
                              hipStream_t stream){
    const float* input   = (const float*)d_in[0];
    const float* n1g     = (const float*)d_in[1];
    const float* n1b     = (const float*)d_in[2];
    const float* map_w   = (const float*)d_in[3];
    const float* map_b   = (const float*)d_in[4];
    const float* gconv   = (const float*)d_in[5];
    const float* tconv_w = (const float*)d_in[6];
    const float* tconv_b = (const float*)d_in[7];
    const float* qkv_w0  = (const float*)d_in[8];
    const float* qkv_b0  = (const float*)d_in[9];
    const float* aproj_w0= (const float*)d_in[10];
    const float* aproj_b0= (const float*)d_in[11];
    const float* tcl_w0  = (const float*)d_in[12];
    const float* tcl_b0  = (const float*)d_in[13];
    const float* qkv_w1  = (const float*)d_in[14];
    const float* qkv_b1  = (const float*)d_in[15];
    const float* aproj_w1= (const float*)d_in[16];
    const float* aproj_b1= (const float*)d_in[17];
    const float* tcl_w1  = (const float*)d_in[18];
    const float* tcl_b1  = (const float*)d_in[19];
    const float* proj_w  = (const float*)d_in[20];
    const float* proj_b  = (const float*)d_in[21];
    const float* n2g     = (const float*)d_in[22];
    const float* n2b     = (const float*)d_in[23];
    const float* mlp_w1  = (const float*)d_in[24];
    const float* mlp_b1  = (const float*)d_in[25];
    const float* mlp_w2  = (const float*)d_in[26];
    const float* mlp_b2  = (const float*)d_in[27];

    const size_t Nt = NTOK;
    size_t need = ( (size_t)900*Nt + 18432 + 2*61440 ) * sizeof(float);
    if (ws_size < need) return;   // insufficient scratch; bail (will show as absmax fail)

    float* ws    = (float*)d_ws;
    float* mean1 = ws;
    float* rstd1 = ws + Nt;
    float* mean2 = ws + 2*Nt;
    float* rstd2 = ws + 3*Nt;
    float* f     = ws + 4*Nt;          // N x 256 (later: y0/y2/y3 columns in place)
    float* a0    = f + 256*Nt;         // N x 192
    float* a1    = a0 + 192*Nt;        // N x 192
    float* outt  = a1 + 192*Nt;        // N x 256
    float* gct   = outt + 256*Nt;      // 8*48*48
    float* wt0   = gct + 18432;        // 5*192*64
    float* wt1   = wt0 + 61440;
    unsigned short* h = (unsigned short*)f;   // bf16 N x 1024, aliases f/a0/(part a1)
    float* y1buf = (float*)d_out;             // scratch N x 64 inside d_out
    float* dout  = (float*)d_out;

    prep_weights<<<64, 256, 0, stream>>>(gconv, tcl_w0, tcl_w1, gct, wt0, wt1);
    ln1_stats<<<NB*TT, 192, 0, stream>>>(input, mean1, rstd1);
    gemm_f<<<dim3(NB*TT,4), 256, 0, stream>>>(input, mean1, rstd1, n1g, n1b, map_w, map_b, f);
    attn_fused<<<NB*TT, 192, 0, stream>>>(f, 128, qkv_w0, qkv_b0, aproj_w0, aproj_b0, a0);
    attn_fused<<<NB*TT, 192, 0, stream>>>(f, 192, qkv_w1, qkv_b1, aproj_w1, aproj_b1, a1);
    y0_kernel<<<NB*TT, 256, 0, stream>>>(f, gct);
    y1_kernel<<<NB*TT, 256, 0, stream>>>(f, tconv_w, tconv_b, y1buf);
    tcl_kernel<<<NB*TT, 256, 0, stream>>>(a0, wt0, tcl_b0, f, 128);
    tcl_kernel<<<NB*TT, 256, 0, stream>>>(a1, wt1, tcl_b1, f, 192);
    gemm_out<<<dim3(NB*TT,4), 256, 0, stream>>>(f, y1buf, input, proj_w, proj_b, outt);
    ln2_stats<<<NTOK/4, 256, 0, stream>>>(outt, mean2, rstd2);
    gemm_h<<<dim3(NB*TT,16), 256, 0, stream>>>(outt, mean2, rstd2, n2g, n2b, mlp_w1, mlp_b1, h);
    gemm_final<<<dim3(NB*TT,4), 256, 0, stream>>>(h, outt, mlp_w2, mlp_b2, dout);
}

// Round 2
// 1540.299 us; speedup vs baseline: 2.5062x; 2.5062x over previous
//
#include <hip/hip_runtime.h>
#include <hip/hip_bf16.h>
#include <math.h>

#define NB 32
#define CC 256
#define TT 64
#define VV 48
#define NTOK (NB*TT*VV)   // 98304
#define LNE 1e-5f

typedef __attribute__((ext_vector_type(8))) __bf16 bf16x8;
typedef __attribute__((ext_vector_type(4))) float f32x4;

__device__ inline float bfbits2f(unsigned int bits){
    union{unsigned int u; float f;} c; c.u = bits<<16; return c.f;
}
__device__ inline unsigned short f2bf(float x){
    union{float f; unsigned int u;} c; c.f = x;
    unsigned int r = (c.u + 0x7fffu + ((c.u>>16)&1u)) >> 16;
    return (unsigned short)r;
}

// ---------------- weight prep: transposed layouts ----------------
__global__ void prep_weights(const float* gconv, const float* tcl0, const float* tcl1,
                             const float* map_w, const float* proj_w,
                             const float* mlp_w1, const float* mlp_w2,
                             float* gct, float* wt0, float* wt1,
                             unsigned short* mapT, unsigned short* projT,
                             unsigned short* w1T, unsigned short* w2T){
    int tid = blockIdx.x*blockDim.x + threadIdx.x;
    int stride = gridDim.x*blockDim.x;
    for (int i = tid; i < 8*48*48; i += stride){
        int g = i/(48*48); int r = i%(48*48); int u = r/48; int v = r%48;
        gct[i] = gconv[(g*48+v)*48+u];
    }
    for (int i = tid; i < 5*192*64; i += stride){
        int kh = i/(192*64); int r = i%(192*64); int ii = r/64; int o = r%64;
        wt0[i] = tcl0[(o*192+ii)*5+kh];
        wt1[i] = tcl1[(o*192+ii)*5+kh];
    }
    // mapT[n][k] = map_w[k][n]  (256x256)
    for (int i = tid; i < 65536; i += stride){
        int n = i>>8, k = i&255;
        mapT[i] = f2bf(map_w[k*256+n]);
        projT[i] = f2bf(proj_w[k*256+n]);
    }
    // w1T[n][k]: n<1024, k<256
    for (int i = tid; i < 262144; i += stride){
        int n = i>>8, k = i&255;
        w1T[i] = f2bf(mlp_w1[k*1024+n]);
    }
    // w2T[n][k]: n<256, k<1024
    for (int i = tid; i < 262144; i += stride){
        int n = i>>10, k = i&1023;
        w2T[i] = f2bf(mlp_w2[k*256+n]);
    }
}

// ---------------- LN1 + transpose -> A1 bf16 [N][256] ----------------
__global__ __launch_bounds__(256) void xpose_ln1(const float* __restrict__ x,
        const float* __restrict__ g, const float* __restrict__ bb,
        unsigned short* __restrict__ A1){
    int bt = blockIdx.x; int b = bt/TT, t = bt%TT;
    __shared__ float X[48*257];
    __shared__ float S[4][48], SS[4][48], sm[48], sv[48];
    int tid = threadIdx.x;
    const float* xb = x + (size_t)b*256*3072 + (size_t)t*48;
    for (int it = 0; it < 12; it++){
        int idx = it*256 + tid;
        int c = idx/12, q = idx%12;
        float4 v = *(const float4*)(xb + (size_t)c*3072 + q*4);
        X[(q*4+0)*257 + c] = v.x;
        X[(q*4+1)*257 + c] = v.y;
        X[(q*4+2)*257 + c] = v.z;
        X[(q*4+3)*257 + c] = v.w;
    }
    __syncthreads();
    if (tid < 192){
        int v = tid % 48, w = tid / 48;
        float s = 0.f, ss = 0.f;
        for (int c = w*64; c < w*64+64; c++){
            float val = X[v*257 + c];
            s += val; ss += val*val;
        }
        S[w][v] = s; SS[w][v] = ss;
    }
    __syncthreads();
    if (tid < 48){
        float s = S[0][tid]+S[1][tid]+S[2][tid]+S[3][tid];
        float q = SS[0][tid]+SS[1][tid]+SS[2][tid]+SS[3][tid];
        float m = s*(1.f/256);
        sm[tid] = m; sv[tid] = rsqrtf(q*(1.f/256) - m*m + LNE);
    }
    __syncthreads();
    int nb = bt*48;
    for (int it = 0; it < 12; it++){
        int idx = it*256 + tid;        // 3072 = 48v x 64cq
        int v = idx>>6, cq = idx&63;
        float m = sm[v], rs = sv[v];
        float4 g4 = *(const float4*)(g + cq*4);
        float4 b4 = *(const float4*)(bb + cq*4);
        ushort4 u;
        u.x = f2bf((X[v*257 + cq*4+0]-m)*rs*g4.x + b4.x);
        u.y = f2bf((X[v*257 + cq*4+1]-m)*rs*g4.y + b4.y);
        u.z = f2bf((X[v*257 + cq*4+2]-m)*rs*g4.z + b4.z);
        u.w = f2bf((X[v*257 + cq*4+3]-m)*rs*g4.w + b4.w);
        *(ushort4*)(A1 + (size_t)(nb+v)*256 + cq*4) = u;
    }
}

// ---------------- swizzled staging: rows x 64 bf16 (128B/row) ----------------
__device__ __forceinline__ void stage_swz(const char* src, size_t rowbytes, char* lds,
                                          int nchunks, int tid){
    for (int c = tid; c < nchunks; c += 256){
        int p = c << 4;
        int r = p >> 7;
        int kl = (p & 127) ^ ((r & 7) << 4);
        __builtin_amdgcn_global_load_lds(
            (const __attribute__((address_space(1))) unsigned int*)(src + (size_t)r*rowbytes + kl),
            (__attribute__((address_space(3))) unsigned int*)(lds + p),
            16, 0, 0);
    }
}

__device__ __forceinline__ bf16x8 frag_ld(const char* lds, int R, int kb){
    return *(const bf16x8*)(lds + R*128 + (kb ^ ((R & 7) << 4)));
}

// ---------------- MFMA GEMM: BM=96, BN=128, BK=64, 4 waves(2x2) ----------------
// A bf16 [M][KTOT] row-major, BT bf16 [N][KTOT] row-major.
// EPI 0: outF = acc + bias (fp32, ncols stride)
// EPI 1: outF(outt) = acc + bias + skip(extra=input NCHW), via Tt transpose
// EPI 2: outH(h) = bf16(gelu(acc + bias)), ncols stride
// EPI 3: outF(dout NCHW) = acc + bias + extra(outt), transposed store
template<int KTOT, int EPI>
__global__ __launch_bounds__(256) void mfma_gemm(
    const unsigned short* __restrict__ A, const unsigned short* __restrict__ BT,
    const float* __restrict__ bias, const float* __restrict__ extra,
    float* __restrict__ outF, unsigned short* __restrict__ outH, int ncols){

    __shared__ __align__(16) char smem[(EPI==1||EPI==3) ? 51200 : 28672];
    char* ldsA = smem;
    char* ldsB = smem + 96*128;
    int tid = threadIdx.x, lane = tid & 63;
    int wid = tid >> 6, wm = wid >> 1, wn = wid & 1;
    int l15 = lane & 15, lq = lane >> 4;
    int m0 = blockIdx.x * 96, n0 = blockIdx.y * 128;
    const size_t arb = KTOT*2, brb = KTOT*2;

    f32x4 acc[3][4];
    #pragma unroll
    for (int i = 0; i < 3; i++)
        #pragma unroll
        for (int j = 0; j < 4; j++){ f32x4 z = {0.f,0.f,0.f,0.f}; acc[i][j] = z; }

    for (int kt = 0; kt < KTOT/64; kt++){
        const char* As = (const char*)A + (size_t)m0*arb + kt*128;
        const char* Bs = (const char*)BT + (size_t)n0*brb + kt*128;
        stage_swz(As, arb, ldsA, 96*8, tid);
        stage_swz(Bs, brb, ldsB, 128*8, tid);
        __syncthreads();
        #pragma unroll
        for (int ks = 0; ks < 2; ks++){
            bf16x8 a[3], b[4];
            int kb = ks*64 + lq*16;
            #pragma unroll
            for (int mf = 0; mf < 3; mf++) a[mf] = frag_ld(ldsA, wm*48 + mf*16 + l15, kb);
            #pragma unroll
            for (int nf = 0; nf < 4; nf++) b[nf] = frag_ld(ldsB, wn*64 + nf*16 + l15, kb);
            #pragma unroll
            for (int mf = 0; mf < 3; mf++)
                #pragma unroll
                for (int nf = 0; nf < 4; nf++)
                    acc[mf][nf] = __builtin_amdgcn_mfma_f32_16x16x32_bf16(a[mf], b[nf], acc[mf][nf], 0, 0, 0);
        }
        __syncthreads();
    }

    if constexpr (EPI == 0){
        #pragma unroll
        for (int nf = 0; nf < 4; nf++){
            int cl = n0 + wn*64 + nf*16 + l15;
            float bb = bias[cl];
            #pragma unroll
            for (int mf = 0; mf < 3; mf++){
                int tl = m0 + wm*48 + mf*16 + lq*4;
                f32x4 v = acc[mf][nf];
                #pragma unroll
                for (int r = 0; r < 4; r++)
                    outF[(size_t)(tl+r)*ncols + cl] = v[r] + bb;
            }
        }
    }
    if constexpr (EPI == 2){
        #pragma unroll
        for (int nf = 0; nf < 4; nf++){
            int cl = n0 + wn*64 + nf*16 + l15;
            float bb = bias[cl];
            #pragma unroll
            for (int mf = 0; mf < 3; mf++){
                int tl = m0 + wm*48 + mf*16 + lq*4;
                f32x4 v = acc[mf][nf];
                #pragma unroll
                for (int r = 0; r < 4; r++){
                    float t0 = v[r] + bb;
                    t0 = 0.5f*t0*(1.0f + erff(t0*0.70710678118f));
                    outH[(size_t)(tl+r)*ncols + cl] = f2bf(t0);
                }
            }
        }
    }
    if constexpr (EPI == 1){
        float* Tt = (float*)smem;  // [128][100]
        #pragma unroll
        for (int nf = 0; nf < 4; nf++){
            int cl = wn*64 + nf*16 + l15;
            float bb = bias[n0 + cl];
            #pragma unroll
            for (int mf = 0; mf < 3; mf++){
                int tl = wm*48 + mf*16 + lq*4;
                f32x4 v = acc[mf][nf];
                #pragma unroll
                for (int r = 0; r < 4; r++)
                    Tt[cl*100 + tl + r] = v[r] + bb;
            }
        }
        __syncthreads();
        // add skip from input (NCHW): thread = (btl, c)
        {
            int btl = tid >> 7, c = tid & 127;
            int gtok = m0 + btl*48;
            int bg = gtok/3072, t = (gtok%3072)/48;
            const float* sp = extra + ((size_t)(bg*256 + n0 + c)*64 + t)*48;
            float* tr = Tt + c*100 + btl*48;
            #pragma unroll
            for (int j = 0; j < 12; j++){
                float4 s4 = *(const float4*)(sp + j*4);
                float4 t4 = *(float4*)(tr + j*4);
                t4.x += s4.x; t4.y += s4.y; t4.z += s4.z; t4.w += s4.w;
                *(float4*)(tr + j*4) = t4;
            }
        }
        __syncthreads();
        // write outt token-major (n fastest within lanes; 16B scattered stores)
        for (int it = 0; it < 12; it++){
            int idx = it*256 + tid;      // 3072 = 32cq x 96nl
            int cq = idx/96, nl = idx%96;
            float4 o;
            o.x = Tt[(cq*4+0)*100 + nl];
            o.y = Tt[(cq*4+1)*100 + nl];
            o.z = Tt[(cq*4+2)*100 + nl];
            o.w = Tt[(cq*4+3)*100 + nl];
            *(float4*)(outF + (size_t)(m0+nl)*256 + n0 + cq*4) = o;
        }
    }
    if constexpr (EPI == 3){
        float* Tt = (float*)smem;  // [128][100]
        #pragma unroll
        for (int nf = 0; nf < 4; nf++){
            int cl = wn*64 + nf*16 + l15;
            float bb = bias[n0 + cl];
            #pragma unroll
            for (int mf = 0; mf < 3; mf++){
                int tl = wm*48 + mf*16 + lq*4;
                f32x4 v = acc[mf][nf];
                #pragma unroll
                for (int r = 0; r < 4; r++){
                    float resid = extra[(size_t)(m0+tl+r)*256 + n0 + cl];
                    Tt[cl*100 + tl + r] = v[r] + bb + resid;
                }
            }
        }
        __syncthreads();
        // transposed NCHW store: thread = (btl, c), 48 contiguous v's
        {
            int btl = tid >> 7, c = tid & 127;
            int gtok = m0 + btl*48;
            int bg = gtok/3072, t = (gtok%3072)/48;
            float* dst = outF + ((size_t)(bg*256 + n0 + c)*64 + t)*48;
            const float* tr = Tt + c*100 + btl*48;
            #pragma unroll
            for (int j = 0; j < 12; j++)
                *(float4*)(dst + j*4) = *(const float4*)(tr + j*4);
        }
    }
}

// ---------------- fused attention (fp32, unchanged) ----------------
__global__ __launch_bounds__(192) void attn_fused(const float* __restrict__ f, int coff,
        const float* __restrict__ qkvw, const float* __restrict__ qkvb,
        const float* __restrict__ pw, const float* __restrict__ pb, float* __restrict__ aout){
    int bt = blockIdx.x; int nb = bt*VV;
    __shared__ float X[48*68];
    __shared__ float Q[48*196];
    int tid = threadIdx.x;
    for (int idx = tid; idx < 768; idx += 192){
        int v = idx/16, c4 = idx%16;
        float4 xv = *(const float4*)(f + (size_t)(nb+v)*256 + coff + c4*4);
        *(float4*)(&X[v*68 + c4*4]) = xv;
    }
    __syncthreads();
    {
        int j = tid;
        float acc[48];
        #pragma unroll
        for (int v = 0; v < 48; v++) acc[v] = 0.f;
        for (int c0 = 0; c0 < 64; c0 += 4){
            float w0 = qkvw[(c0+0)*192+j], w1 = qkvw[(c0+1)*192+j];
            float w2 = qkvw[(c0+2)*192+j], w3 = qkvw[(c0+3)*192+j];
            #pragma unroll
            for (int v = 0; v < 48; v++){
                float4 xv = *(const float4*)(&X[v*68 + c0]);
                acc[v] += xv.x*w0 + xv.y*w1 + xv.z*w2 + xv.w*w3;
            }
        }
        float bj = qkvb[j];
        #pragma unroll
        for (int v = 0; v < 48; v++) Q[v*196 + j] = acc[v] + bj;
    }
    __syncthreads();
    {
        int u = tid % 16, gh = tid / 16, g = gh >> 2, h = gh & 3;
        int ru = g*16+u;
        float qreg[16];
        #pragma unroll
        for (int d = 0; d < 16; d++) qreg[d] = Q[ru*196 + h*16 + d];
        float sc[16]; float mx = -1e30f;
        #pragma unroll
        for (int w = 0; w < 16; w++){
            float s = 0.f;
            #pragma unroll
            for (int d = 0; d < 16; d++) s += qreg[d]*Q[(g*16+w)*196 + 64 + h*16 + d];
            s *= 0.5f; sc[w] = s; mx = fmaxf(mx, s);
        }
        float sum = 0.f;
        #pragma unroll
        for (int w = 0; w < 16; w++){ sc[w] = expf(sc[w]-mx); sum += sc[w]; }
        float inv = 1.0f/sum;
        float ol[16];
        #pragma unroll
        for (int d = 0; d < 16; d++){
            float o = 0.f;
            #pragma unroll
            for (int w = 0; w < 16; w++) o += sc[w]*Q[(g*16+w)*196 + 128 + h*16 + d];
            ol[d] = o*inv;
        }
        #pragma unroll
        for (int d = 0; d < 16; d++) X[ru*68 + h*16 + d] = ol[d];
    }
    __syncthreads();
    {
        int j = tid;
        float acc[48];
        #pragma unroll
        for (int v = 0; v < 48; v++) acc[v] = 0.f;
        for (int c0 = 0; c0 < 64; c0 += 4){
            float w0 = pw[(c0+0)*192+j], w1 = pw[(c0+1)*192+j];
            float w2 = pw[(c0+2)*192+j], w3 = pw[(c0+3)*192+j];
            #pragma unroll
            for (int v = 0; v < 48; v++){
                float4 xv = *(const float4*)(&X[v*68 + c0]);
                acc[v] += xv.x*w0 + xv.y*w1 + xv.z*w2 + xv.w*w3;
            }
        }
        float bj = pb[j];
        #pragma unroll
        for (int v = 0; v < 48; v++) aout[(size_t)(nb+v)*192 + j] = acc[v] + bj;
    }
}

// ---------------- y0: grouped V-mix -> ybf cols 0..63 (bf16) ----------------
__global__ __launch_bounds__(256) void y0_kernel(const float* __restrict__ f,
        const float* __restrict__ gct, unsigned short* __restrict__ ybf){
    int bt = blockIdx.x; int nb = bt*VV;
    __shared__ float X[48*68];
    for (int it = 0; it < 3; it++){
        int idx = it*256 + threadIdx.x;
        int v = idx/16, c4 = idx%16;
        float4 xv = *(const float4*)(f + (size_t)(nb+v)*256 + c4*4);
        *(float4*)(&X[v*68 + c4*4]) = xv;
    }
    __syncthreads();
    int c = threadIdx.x % 64, vv = threadIdx.x / 64;
    int g = c >> 3;
    float acc[12] = {};
    for (int u = 0; u < 48; u++){
        float xv = X[u*68 + c];
        const float* gr = gct + (size_t)(g*48+u)*48 + vv*12;
        float4 g0 = *(const float4*)(gr);
        float4 g1 = *(const float4*)(gr+4);
        float4 g2 = *(const float4*)(gr+8);
        acc[0]+=xv*g0.x; acc[1]+=xv*g0.y; acc[2]+=xv*g0.z;  acc[3]+=xv*g0.w;
        acc[4]+=xv*g1.x; acc[5]+=xv*g1.y; acc[6]+=xv*g1.z;  acc[7]+=xv*g1.w;
        acc[8]+=xv*g2.x; acc[9]+=xv*g2.y; acc[10]+=xv*g2.z; acc[11]+=xv*g2.w;
    }
    #pragma unroll
    for (int j = 0; j < 12; j++)
        ybf[(size_t)(nb + vv*12 + j)*256 + c] = f2bf(acc[j]);
}

// ---------------- y1: grouped temporal conv (k=7) -> ybf cols 64..127 ----------------
__global__ __launch_bounds__(256) void y1_kernel(const float* __restrict__ f,
        const float* __restrict__ tw, const float* __restrict__ tb, unsigned short* __restrict__ ybf){
    int bt = blockIdx.x; int b = bt/TT, t = bt%TT;
    int o = threadIdx.x % 64, vv = threadIdx.x / 64;
    int g = o >> 3;
    float bv = tb[o];
    float acc[12];
    #pragma unroll
    for (int j = 0; j < 12; j++) acc[j] = bv;
    for (int kh = 0; kh < 7; kh++){
        int tt = t + kh - 3;
        if (tt < 0 || tt >= TT) continue;
        float wk[8];
        #pragma unroll
        for (int ci = 0; ci < 8; ci++) wk[ci] = tw[(o*8+ci)*7 + kh];
        int nb2 = (b*TT+tt)*VV;
        #pragma unroll
        for (int j = 0; j < 12; j++){
            const float* fr = f + (size_t)(nb2 + vv*12 + j)*256 + 64 + g*8;
            float4 f0 = *(const float4*)fr;
            float4 f1 = *(const float4*)(fr+4);
            acc[j] += f0.x*wk[0]+f0.y*wk[1]+f0.z*wk[2]+f0.w*wk[3]
                    + f1.x*wk[4]+f1.y*wk[5]+f1.z*wk[6]+f1.w*wk[7];
        }
    }
    int nb = bt*VV;
    #pragma unroll
    for (int j = 0; j < 12; j++)
        ybf[(size_t)(nb + vv*12 + j)*256 + 64 + o] = f2bf(acc[j]);
}

// ---------------- y2/y3: causal temporal conv k=5 -> ybf cols outoff.. ----------------
__global__ __launch_bounds__(256) void tcl_kernel(const float* __restrict__ a,
        const float* __restrict__ wt, const float* __restrict__ tb,
        unsigned short* __restrict__ ybf, int outoff){
    int bt = blockIdx.x; int b = bt/TT, t = bt%TT;
    __shared__ float As[48*196];
    int o = threadIdx.x % 64, vv = threadIdx.x / 64;
    float bvv = tb[o];
    float acc[12];
    #pragma unroll
    for (int j = 0; j < 12; j++) acc[j] = bvv;
    for (int kh = 0; kh < 5; kh++){
        int tt = t + kh - 4;
        if (tt < 0) continue;
        __syncthreads();
        int nb2 = (b*TT+tt)*VV;
        for (int it = 0; it < 9; it++){
            int idx = it*256 + threadIdx.x;
            int v = idx/48, c4 = idx%48;
            *(float4*)(&As[v*196 + c4*4]) = *(const float4*)(a + (size_t)(nb2+v)*192 + c4*4);
        }
        __syncthreads();
        const float* wk = wt + kh*192*64;
        for (int i0 = 0; i0 < 192; i0 += 4){
            float w0 = wk[(i0+0)*64+o];
            float w1 = wk[(i0+1)*64+o];
            float w2 = wk[(i0+2)*64+o];
            float w3 = wk[(i0+3)*64+o];
            #pragma unroll
            for (int j = 0; j < 12; j++){
                float4 av = *(const float4*)(&As[(vv*12+j)*196 + i0]);
                acc[j] += av.x*w0 + av.y*w1 + av.z*w2 + av.w*w3;
            }
        }
    }
    int nb = bt*VV;
    #pragma unroll
    for (int j = 0; j < 12; j++)
        ybf[(size_t)(nb + vv*12 + j)*256 + outoff + o] = f2bf(acc[j]);
}

// ---------------- LN2 fused: outt -> xn bf16 ----------------
__global__ __launch_bounds__(256) void ln2xn(const float* __restrict__ outt,
        const float* __restrict__ g, const float* __restrict__ bb, unsigned short* __restrict__ xn){
    int n = blockIdx.x*4 + (threadIdx.x >> 6);
    int lane = threadIdx.x & 63;
    const float* row = outt + (size_t)n*256;
    float4 v = *(const float4*)(row + lane*4);
    float s = v.x+v.y+v.z+v.w;
    float ss = v.x*v.x+v.y*v.y+v.z*v.z+v.w*v.w;
    for (int off = 32; off; off >>= 1){ s += __shfl_xor(s, off); ss += __shfl_xor(ss, off); }
    float m = s*(1.0f/256), rs = rsqrtf(ss*(1.0f/256) - m*m + LNE);
    float4 g4 = *(const float4*)(g + lane*4);
    float4 b4 = *(const float4*)(bb + lane*4);
    ushort4 u;
    u.x = f2bf((v.x-m)*rs*g4.x + b4.x);
    u.y = f2bf((v.y-m)*rs*g4.y + b4.y);
    u.z = f2bf((v.z-m)*rs*g4.z + b4.z);
    u.w = f2bf((v.w-m)*rs*g4.w + b4.w);
    *(ushort4*)(xn + (size_t)n*256 + lane*4) = u;
}

extern "C" void kernel_launch(void* const* d_in, const int* in_sizes, int n_in,
                              void* d_out, int out_size, void* d_ws, size_t ws_size,
                              hipStream_t stream){
    const float* input   = (const float*)d_in[0];
    const float* n1g     = (const float*)d_in[1];
    const float* n1b     = (const float*)d_in[2];
    const float* map_w   = (const float*)d_in[3];
    const float* map_b   = (const float*)d_in[4];
    const float* gconv   = (const float*)d_in[5];
    const float* tconv_w = (const float*)d_in[6];
    const float* tconv_b = (const float*)d_in[7];
    const float* qkv_w0  = (const float*)d_in[8];
    const float* qkv_b0  = (const float*)d_in[9];
    const float* aproj_w0= (const float*)d_in[10];
    const float* aproj_b0= (const float*)d_in[11];
    const float* tcl_w0  = (const float*)d_in[12];
    const float* tcl_b0  = (const float*)d_in[13];
    const float* qkv_w1  = (const float*)d_in[14];
    const float* qkv_b1  = (const float*)d_in[15];
    const float* aproj_w1= (const float*)d_in[16];
    const float* aproj_b1= (const float*)d_in[17];
    const float* tcl_w1  = (const float*)d_in[18];
    const float* tcl_b1  = (const float*)d_in[19];
    const float* proj_w  = (const float*)d_in[20];
    const float* proj_b  = (const float*)d_in[21];
    const float* n2g     = (const float*)d_in[22];
    const float* n2b     = (const float*)d_in[23];
    const float* mlp_w1  = (const float*)d_in[24];
    const float* mlp_b1  = (const float*)d_in[25];
    const float* mlp_w2  = (const float*)d_in[26];
    const float* mlp_b2  = (const float*)d_in[27];

    const size_t Nt = NTOK;
    size_t need = ((size_t)896*Nt + 18432 + 2*61440 + 327680) * sizeof(float);
    if (ws_size < need) return;

    float* ws   = (float*)d_ws;
    float* outt = ws;                              // 256 Nt
    float* f    = outt + (size_t)256*Nt;           // 256 Nt
    float* a0   = f + (size_t)256*Nt;              // 192 Nt (reused for a1)
    float* wpad = a0 + (size_t)192*Nt;             // 64 Nt (tail for h)
    unsigned short* A1 = (unsigned short*)(wpad + (size_t)64*Nt);  // 128 Nt f32-units
    float* gct  = (float*)((unsigned short*)A1 + (size_t)256*Nt);
    float* wt0  = gct + 18432;
    float* wt1  = wt0 + 61440;
    unsigned short* mapT  = (unsigned short*)(wt1 + 61440);
    unsigned short* projT = mapT + 65536;
    unsigned short* w1T   = projT + 65536;
    unsigned short* w2T   = w1T + 262144;

    unsigned short* h   = (unsigned short*)f;      // 512 Nt units: f+a0+wpad
    unsigned short* xn  = A1;                      // reuses A1 after gemm_f
    unsigned short* ybf = (unsigned short*)d_out;  // bf16 N x 256 scratch
    float* dout = (float*)d_out;

    prep_weights<<<256, 256, 0, stream>>>(gconv, tcl_w0, tcl_w1, map_w, proj_w, mlp_w1, mlp_w2,
                                          gct, wt0, wt1, mapT, projT, w1T, w2T);
    xpose_ln1<<<NB*TT, 256, 0, stream>>>(input, n1g, n1b, A1);
    mfma_gemm<256,0><<<dim3(1024,2), 256, 0, stream>>>(A1, mapT, map_b, nullptr, f, nullptr, 256);
    attn_fused<<<NB*TT, 192, 0, stream>>>(f, 128, qkv_w0, qkv_b0, aproj_w0, aproj_b0, a0);
    tcl_kernel<<<NB*TT, 256, 0, stream>>>(a0, wt0, tcl_b0, ybf, 128);
    attn_fused<<<NB*TT, 192, 0, stream>>>(f, 192, qkv_w1, qkv_b1, aproj_w1, aproj_b1, a0);
    tcl_kernel<<<NB*TT, 256, 0, stream>>>(a0, wt1, tcl_b1, ybf, 192);
    y0_kernel<<<NB*TT, 256, 0, stream>>>(f, gct, ybf);
    y1_kernel<<<NB*TT, 256, 0, stream>>>(f, tconv_w, tconv_b, ybf);
    mfma_gemm<256,1><<<dim3(1024,2), 256, 0, stream>>>(ybf, projT, proj_b, input, outt, nullptr, 256);
    ln2xn<<<NTOK/4, 256, 0, stream>>>(outt, n2g, n2b, xn);
    mfma_gemm<256,2><<<dim3(1024,8), 256, 0, stream>>>(xn, w1T, mlp_b1, nullptr, nullptr, h, 1024);
    mfma_gemm<1024,3><<<dim3(1024,2), 256, 0, stream>>>(h, w2T, mlp_b2, outt, dout, nullptr, 256);
}

// Round 3
// 968.849 us; speedup vs baseline: 3.9845x; 1.5898x over previous
//
#include <hip/hip_runtime.h>
#include <hip/hip_bf16.h>
#include <math.h>

#define NB 32
#define CC 256
#define TT 64
#define VV 48
#define NTOK (NB*TT*VV)   // 98304
#define LNE 1e-5f
// padded attention-output layout: per batch 4*48 zero rows + 64*48 data rows
#define PROWS 3264        // (4+64)*48
#define A0P_USH ((size_t)NB*PROWS*192)

typedef __attribute__((ext_vector_type(8))) __bf16 bf16x8;
typedef __attribute__((ext_vector_type(4))) float f32x4;

__device__ inline float bfbits2f(unsigned int bits){
    union{unsigned int u; float f;} c; c.u = bits<<16; return c.f;
}
__device__ inline unsigned short f2bf(float x){
    union{float f; unsigned int u;} c; c.f = x;
    unsigned int r = (c.u + 0x7fffu + ((c.u>>16)&1u)) >> 16;
    return (unsigned short)r;
}

// ---------------- weight prep ----------------
__global__ void prep_weights(const float* gconv, const float* tcl0, const float* tcl1,
                             const float* map_w, const float* proj_w,
                             const float* mlp_w1, const float* mlp_w2,
                             float* gct,
                             unsigned short* mapT, unsigned short* projT,
                             unsigned short* w1T, unsigned short* w2T,
                             unsigned short* tclT0, unsigned short* tclT1){
    int tid = blockIdx.x*blockDim.x + threadIdx.x;
    int stride = gridDim.x*blockDim.x;
    for (int i = tid; i < 8*48*48; i += stride){
        int g = i/(48*48); int r = i%(48*48); int u = r/48; int v = r%48;
        gct[i] = gconv[(g*48+v)*48+u];
    }
    // tclT[o][kh*192+c] = tcl[(o*192+c)*5+kh]   (64 x 960)
    for (int i = tid; i < 64*960; i += stride){
        int o = i/960, col = i%960, kh = col/192, c = col%192;
        tclT0[i] = f2bf(tcl0[(o*192+c)*5+kh]);
        tclT1[i] = f2bf(tcl1[(o*192+c)*5+kh]);
    }
    // mapT[n][k] = map_w[k][n]  (256x256)
    for (int i = tid; i < 65536; i += stride){
        int n = i>>8, k = i&255;
        mapT[i] = f2bf(map_w[k*256+n]);
        projT[i] = f2bf(proj_w[k*256+n]);
    }
    for (int i = tid; i < 262144; i += stride){
        int n = i>>8, k = i&255;
        w1T[i] = f2bf(mlp_w1[k*1024+n]);
    }
    for (int i = tid; i < 262144; i += stride){
        int n = i>>10, k = i&1023;
        w2T[i] = f2bf(mlp_w2[k*256+n]);
    }
}

// ---------------- LN1 + transpose -> A1 bf16 [N][256] ----------------
__global__ __launch_bounds__(256) void xpose_ln1(const float* __restrict__ x,
        const float* __restrict__ g, const float* __restrict__ bb,
        unsigned short* __restrict__ A1){
    int bt = blockIdx.x; int b = bt/TT, t = bt%TT;
    __shared__ float X[48*257];
    __shared__ float S[4][48], SS[4][48], sm[48], sv[48];
    int tid = threadIdx.x;
    const float* xb = x + (size_t)b*256*3072 + (size_t)t*48;
    for (int it = 0; it < 12; it++){
        int idx = it*256 + tid;
        int c = idx/12, q = idx%12;
        float4 v = *(const float4*)(xb + (size_t)c*3072 + q*4);
        X[(q*4+0)*257 + c] = v.x;
        X[(q*4+1)*257 + c] = v.y;
        X[(q*4+2)*257 + c] = v.z;
        X[(q*4+3)*257 + c] = v.w;
    }
    __syncthreads();
    if (tid < 192){
        int v = tid % 48, w = tid / 48;
        float s = 0.f, ss = 0.f;
        for (int c = w*64; c < w*64+64; c++){
            float val = X[v*257 + c];
            s += val; ss += val*val;
        }
        S[w][v] = s; SS[w][v] = ss;
    }
    __syncthreads();
    if (tid < 48){
        float s = S[0][tid]+S[1][tid]+S[2][tid]+S[3][tid];
        float q = SS[0][tid]+SS[1][tid]+SS[2][tid]+SS[3][tid];
        float m = s*(1.f/256);
        sm[tid] = m; sv[tid] = rsqrtf(q*(1.f/256) - m*m + LNE);
    }
    __syncthreads();
    int nb = bt*48;
    for (int it = 0; it < 12; it++){
        int idx = it*256 + tid;
        int v = idx>>6, cq = idx&63;
        float m = sm[v], rs = sv[v];
        float4 g4 = *(const float4*)(g + cq*4);
        float4 b4 = *(const float4*)(bb + cq*4);
        ushort4 u;
        u.x = f2bf((X[v*257 + cq*4+0]-m)*rs*g4.x + b4.x);
        u.y = f2bf((X[v*257 + cq*4+1]-m)*rs*g4.y + b4.y);
        u.z = f2bf((X[v*257 + cq*4+2]-m)*rs*g4.z + b4.z);
        u.w = f2bf((X[v*257 + cq*4+3]-m)*rs*g4.w + b4.w);
        *(ushort4*)(A1 + (size_t)(nb+v)*256 + cq*4) = u;
    }
}

// ---------------- swizzled staging: rows x 64 bf16 (128B/row in LDS) ----------------
__device__ __forceinline__ void stage_swz(const char* src, size_t rowbytes, char* lds,
                                          int nchunks, int tid){
    for (int c = tid; c < nchunks; c += 256){
        int p = c << 4;
        int r = p >> 7;
        int kl = (p & 127) ^ ((r & 7) << 4);
        __builtin_amdgcn_global_load_lds(
            (const __attribute__((address_space(1))) unsigned int*)(src + (size_t)r*rowbytes + kl),
            (__attribute__((address_space(3))) unsigned int*)(lds + p),
            16, 0, 0);
    }
}

__device__ __forceinline__ bf16x8 frag_ld(const char* lds, int R, int kb){
    return *(const bf16x8*)(lds + R*128 + (kb ^ ((R & 7) << 4)));
}

// ---------------- MFMA GEMM: BM=96, BN=128, BK=64, 4 waves(2x2) ----------------
template<int KTOT, int EPI>
__global__ __launch_bounds__(256) void mfma_gemm(
    const unsigned short* __restrict__ A, const unsigned short* __restrict__ BT,
    const float* __restrict__ bias, const float* __restrict__ extra,
    float* __restrict__ outF, unsigned short* __restrict__ outH, int ncols){

    __shared__ __align__(16) char smem[(EPI==1||EPI==3) ? 51200 : 28672];
    char* ldsA = smem;
    char* ldsB = smem + 96*128;
    int tid = threadIdx.x, lane = tid & 63;
    int wid = tid >> 6, wm = wid >> 1, wn = wid & 1;
    int l15 = lane & 15, lq = lane >> 4;
    int m0 = blockIdx.x * 96, n0 = blockIdx.y * 128;
    const size_t arb = KTOT*2, brb = KTOT*2;

    f32x4 acc[3][4];
    #pragma unroll
    for (int i = 0; i < 3; i++)
        #pragma unroll
        for (int j = 0; j < 4; j++){ f32x4 z = {0.f,0.f,0.f,0.f}; acc[i][j] = z; }

    for (int kt = 0; kt < KTOT/64; kt++){
        const char* As = (const char*)A + (size_t)m0*arb + kt*128;
        const char* Bs = (const char*)BT + (size_t)n0*brb + kt*128;
        stage_swz(As, arb, ldsA, 96*8, tid);
        stage_swz(Bs, brb, ldsB, 128*8, tid);
        __syncthreads();
        #pragma unroll
        for (int ks = 0; ks < 2; ks++){
            bf16x8 a[3], b[4];
            int kb = ks*64 + lq*16;
            #pragma unroll
            for (int mf = 0; mf < 3; mf++) a[mf] = frag_ld(ldsA, wm*48 + mf*16 + l15, kb);
            #pragma unroll
            for (int nf = 0; nf < 4; nf++) b[nf] = frag_ld(ldsB, wn*64 + nf*16 + l15, kb);
            #pragma unroll
            for (int mf = 0; mf < 3; mf++)
                #pragma unroll
                for (int nf = 0; nf < 4; nf++)
                    acc[mf][nf] = __builtin_amdgcn_mfma_f32_16x16x32_bf16(a[mf], b[nf], acc[mf][nf], 0, 0, 0);
        }
        __syncthreads();
    }

    if constexpr (EPI == 0){
        #pragma unroll
        for (int nf = 0; nf < 4; nf++){
            int cl = n0 + wn*64 + nf*16 + l15;
            float bb = bias[cl];
            #pragma unroll
            for (int mf = 0; mf < 3; mf++){
                int tl = m0 + wm*48 + mf*16 + lq*4;
                f32x4 v = acc[mf][nf];
                #pragma unroll
                for (int r = 0; r < 4; r++)
                    outF[(size_t)(tl+r)*ncols + cl] = v[r] + bb;
            }
        }
    }
    if constexpr (EPI == 2){
        #pragma unroll
        for (int nf = 0; nf < 4; nf++){
            int cl = n0 + wn*64 + nf*16 + l15;
            float bb = bias[cl];
            #pragma unroll
            for (int mf = 0; mf < 3; mf++){
                int tl = m0 + wm*48 + mf*16 + lq*4;
                f32x4 v = acc[mf][nf];
                #pragma unroll
                for (int r = 0; r < 4; r++){
                    float t0 = v[r] + bb;
                    t0 = 0.5f*t0*(1.0f + erff(t0*0.70710678118f));
                    outH[(size_t)(tl+r)*ncols + cl] = f2bf(t0);
                }
            }
        }
    }
    if constexpr (EPI == 1){
        float* Tt = (float*)smem;  // [128][100]
        #pragma unroll
        for (int nf = 0; nf < 4; nf++){
            int cl = wn*64 + nf*16 + l15;
            float bb = bias[n0 + cl];
            #pragma unroll
            for (int mf = 0; mf < 3; mf++){
                int tl = wm*48 + mf*16 + lq*4;
                f32x4 v = acc[mf][nf];
                #pragma unroll
                for (int r = 0; r < 4; r++)
                    Tt[cl*100 + tl + r] = v[r] + bb;
            }
        }
        __syncthreads();
        {
            int btl = tid >> 7, c = tid & 127;
            int gtok = m0 + btl*48;
            int bg = gtok/3072, t = (gtok%3072)/48;
            const float* sp = extra + ((size_t)(bg*256 + n0 + c)*64 + t)*48;
            float* tr = Tt + c*100 + btl*48;
            #pragma unroll
            for (int j = 0; j < 12; j++){
                float4 s4 = *(const float4*)(sp + j*4);
                float4 t4 = *(float4*)(tr + j*4);
                t4.x += s4.x; t4.y += s4.y; t4.z += s4.z; t4.w += s4.w;
                *(float4*)(tr + j*4) = t4;
            }
        }
        __syncthreads();
        for (int it = 0; it < 12; it++){
            int idx = it*256 + tid;
            int cq = idx/96, nl = idx%96;
            float4 o;
            o.x = Tt[(cq*4+0)*100 + nl];
            o.y = Tt[(cq*4+1)*100 + nl];
            o.z = Tt[(cq*4+2)*100 + nl];
            o.w = Tt[(cq*4+3)*100 + nl];
            *(float4*)(outF + (size_t)(m0+nl)*256 + n0 + cq*4) = o;
        }
    }
    if constexpr (EPI == 3){
        float* Tt = (float*)smem;  // [128][100]
        #pragma unroll
        for (int nf = 0; nf < 4; nf++){
            int cl = wn*64 + nf*16 + l15;
            float bb = bias[n0 + cl];
            #pragma unroll
            for (int mf = 0; mf < 3; mf++){
                int tl = wm*48 + mf*16 + lq*4;
                f32x4 v = acc[mf][nf];
                #pragma unroll
                for (int r = 0; r < 4; r++){
                    float resid = extra[(size_t)(m0+tl+r)*256 + n0 + cl];
                    Tt[cl*100 + tl + r] = v[r] + bb + resid;
                }
            }
        }
        __syncthreads();
        {
            int btl = tid >> 7, c = tid & 127;
            int gtok = m0 + btl*48;
            int bg = gtok/3072, t = (gtok%3072)/48;
            float* dst = outF + ((size_t)(bg*256 + n0 + c)*64 + t)*48;
            const float* tr = Tt + c*100 + btl*48;
            #pragma unroll
            for (int j = 0; j < 12; j++)
                *(float4*)(dst + j*4) = *(const float4*)(tr + j*4);
        }
    }
}

// ---------------- tcl as MFMA GEMM: K=960 via 5 shifted taps, BM=192, BN=64 ----------------
__global__ __launch_bounds__(256) void tcl_mfma(const unsigned short* __restrict__ A0p,
        const unsigned short* __restrict__ BT, const float* __restrict__ tb,
        unsigned short* __restrict__ ybf, int outoff){
    __shared__ __align__(16) char smem[192*128 + 64*128];
    char* ldsA = smem;
    char* ldsB = smem + 192*128;
    int tid = threadIdx.x, lane = tid & 63;
    int wid = tid >> 6;
    int l15 = lane & 15, lq = lane >> 4;
    int m0 = blockIdx.x * 192;
    int b = m0 / 3072;
    long brow0 = (long)b*PROWS + 192 + (m0 - b*3072);   // padded row of first token

    f32x4 acc[3][4];
    #pragma unroll
    for (int i = 0; i < 3; i++)
        #pragma unroll
        for (int j = 0; j < 4; j++){ f32x4 z = {0.f,0.f,0.f,0.f}; acc[i][j] = z; }

    for (int kh = 0; kh < 5; kh++){
        long rowA = brow0 + (long)(kh-4)*48;
        for (int kc3 = 0; kc3 < 3; kc3++){
            int kt = kh*3 + kc3;
            const char* As = (const char*)A0p + rowA*384 + kc3*128;
            const char* Bs = (const char*)BT + kt*128;
            stage_swz(As, 384, ldsA, 192*8, tid);
            stage_swz(Bs, 1920, ldsB, 64*8, tid);
            __syncthreads();
            #pragma unroll
            for (int ks = 0; ks < 2; ks++){
                bf16x8 a[3], bb[4];
                int kb = ks*64 + lq*16;
                #pragma unroll
                for (int mf = 0; mf < 3; mf++) a[mf] = frag_ld(ldsA, wid*48 + mf*16 + l15, kb);
                #pragma unroll
                for (int nf = 0; nf < 4; nf++) bb[nf] = frag_ld(ldsB, nf*16 + l15, kb);
                #pragma unroll
                for (int mf = 0; mf < 3; mf++)
                    #pragma unroll
                    for (int nf = 0; nf < 4; nf++)
                        acc[mf][nf] = __builtin_amdgcn_mfma_f32_16x16x32_bf16(a[mf], bb[nf], acc[mf][nf], 0, 0, 0);
            }
            __syncthreads();
        }
    }
    #pragma unroll
    for (int nf = 0; nf < 4; nf++){
        int col = nf*16 + l15;
        float bb = tb[col];
        #pragma unroll
        for (int mf = 0; mf < 3; mf++){
            int tok = m0 + wid*48 + mf*16 + lq*4;
            f32x4 v = acc[mf][nf];
            #pragma unroll
            for (int r = 0; r < 4; r++)
                ybf[(size_t)(tok+r)*256 + outoff + col] = f2bf(v[r] + bb);
        }
    }
}

// ---------------- fused attention (fp32 compute, bf16 padded output) ----------------
__global__ __launch_bounds__(192) void attn_fused(const float* __restrict__ f, int coff,
        const float* __restrict__ qkvw, const float* __restrict__ qkvb,
        const float* __restrict__ pw, const float* __restrict__ pb,
        unsigned short* __restrict__ aout){
    int bt = blockIdx.x; int nb = bt*VV;
    int b = bt >> 6, t = bt & 63;
    size_t pr = (size_t)b*PROWS + 192 + (size_t)t*48;
    __shared__ float X[48*68];
    __shared__ float Q[48*196];
    int tid = threadIdx.x;
    for (int idx = tid; idx < 768; idx += 192){
        int v = idx/16, c4 = idx%16;
        float4 xv = *(const float4*)(f + (size_t)(nb+v)*256 + coff + c4*4);
        *(float4*)(&X[v*68 + c4*4]) = xv;
    }
    __syncthreads();
    {
        int j = tid;
        float acc[48];
        #pragma unroll
        for (int v = 0; v < 48; v++) acc[v] = 0.f;
        for (int c0 = 0; c0 < 64; c0 += 4){
            float w0 = qkvw[(c0+0)*192+j], w1 = qkvw[(c0+1)*192+j];
            float w2 = qkvw[(c0+2)*192+j], w3 = qkvw[(c0+3)*192+j];
            #pragma unroll
            for (int v = 0; v < 48; v++){
                float4 xv = *(const float4*)(&X[v*68 + c0]);
                acc[v] += xv.x*w0 + xv.y*w1 + xv.z*w2 + xv.w*w3;
            }
        }
        float bj = qkvb[j];
        #pragma unroll
        for (int v = 0; v < 48; v++) Q[v*196 + j] = acc[v] + bj;
    }
    __syncthreads();
    {
        int u = tid % 16, gh = tid / 16, g = gh >> 2, h = gh & 3;
        int ru = g*16+u;
        float qreg[16];
        #pragma unroll
        for (int d = 0; d < 16; d++) qreg[d] = Q[ru*196 + h*16 + d];
        float sc[16]; float mx = -1e30f;
        #pragma unroll
        for (int w = 0; w < 16; w++){
            float s = 0.f;
            #pragma unroll
            for (int d = 0; d < 16; d++) s += qreg[d]*Q[(g*16+w)*196 + 64 + h*16 + d];
            s *= 0.5f; sc[w] = s; mx = fmaxf(mx, s);
        }
        float sum = 0.f;
        #pragma unroll
        for (int w = 0; w < 16; w++){ sc[w] = expf(sc[w]-mx); sum += sc[w]; }
        float inv = 1.0f/sum;
        float ol[16];
        #pragma unroll
        for (int d = 0; d < 16; d++){
            float o = 0.f;
            #pragma unroll
            for (int w = 0; w < 16; w++) o += sc[w]*Q[(g*16+w)*196 + 128 + h*16 + d];
            ol[d] = o*inv;
        }
        #pragma unroll
        for (int d = 0; d < 16; d++) X[ru*68 + h*16 + d] = ol[d];
    }
    __syncthreads();
    {
        int j = tid;
        float acc[48];
        #pragma unroll
        for (int v = 0; v < 48; v++) acc[v] = 0.f;
        for (int c0 = 0; c0 < 64; c0 += 4){
            float w0 = pw[(c0+0)*192+j], w1 = pw[(c0+1)*192+j];
            float w2 = pw[(c0+2)*192+j], w3 = pw[(c0+3)*192+j];
            #pragma unroll
            for (int v = 0; v < 48; v++){
                float4 xv = *(const float4*)(&X[v*68 + c0]);
                acc[v] += xv.x*w0 + xv.y*w1 + xv.z*w2 + xv.w*w3;
            }
        }
        float bj = pb[j];
        #pragma unroll
        for (int v = 0; v < 48; v++) aout[(pr+v)*192 + j] = f2bf(acc[v] + bj);
    }
}

// ---------------- y0: grouped V-mix -> ybf cols 0..63 (bf16) ----------------
__global__ __launch_bounds__(256) void y0_kernel(const float* __restrict__ f,
        const float* __restrict__ gct, unsigned short* __restrict__ ybf){
    int bt = blockIdx.x; int nb = bt*VV;
    __shared__ float X[48*68];
    for (int it = 0; it < 3; it++){
        int idx = it*256 + threadIdx.x;
        int v = idx/16, c4 = idx%16;
        float4 xv = *(const float4*)(f + (size_t)(nb+v)*256 + c4*4);
        *(float4*)(&X[v*68 + c4*4]) = xv;
    }
    __syncthreads();
    int c = threadIdx.x % 64, vv = threadIdx.x / 64;
    int g = c >> 3;
    float acc[12] = {};
    for (int u = 0; u < 48; u++){
        float xv = X[u*68 + c];
        const float* gr = gct + (size_t)(g*48+u)*48 + vv*12;
        float4 g0 = *(const float4*)(gr);
        float4 g1 = *(const float4*)(gr+4);
        float4 g2 = *(const float4*)(gr+8);
        acc[0]+=xv*g0.x; acc[1]+=xv*g0.y; acc[2]+=xv*g0.z;  acc[3]+=xv*g0.w;
        acc[4]+=xv*g1.x; acc[5]+=xv*g1.y; acc[6]+=xv*g1.z;  acc[7]+=xv*g1.w;
        acc[8]+=xv*g2.x; acc[9]+=xv*g2.y; acc[10]+=xv*g2.z; acc[11]+=xv*g2.w;
    }
    #pragma unroll
    for (int j = 0; j < 12; j++)
        ybf[(size_t)(nb + vv*12 + j)*256 + c] = f2bf(acc[j]);
}

// ---------------- y1: grouped temporal conv (k=7) -> ybf cols 64..127 ----------------
__global__ __launch_bounds__(256) void y1_kernel(const float* __restrict__ f,
        const float* __restrict__ tw, const float* __restrict__ tb, unsigned short* __restrict__ ybf){
    int bt = blockIdx.x; int b = bt/TT, t = bt%TT;
    int o = threadIdx.x % 64, vv = threadIdx.x / 64;
    int g = o >> 3;
    float bv = tb[o];
    float acc[12];
    #pragma unroll
    for (int j = 0; j < 12; j++) acc[j] = bv;
    for (int kh = 0; kh < 7; kh++){
        int tt = t + kh - 3;
        if (tt < 0 || tt >= TT) continue;
        float wk[8];
        #pragma unroll
        for (int ci = 0; ci < 8; ci++) wk[ci] = tw[(o*8+ci)*7 + kh];
        int nb2 = (b*TT+tt)*VV;
        #pragma unroll
        for (int j = 0; j < 12; j++){
            const float* fr = f + (size_t)(nb2 + vv*12 + j)*256 + 64 + g*8;
            float4 f0 = *(const float4*)fr;
            float4 f1 = *(const float4*)(fr+4);
            acc[j] += f0.x*wk[0]+f0.y*wk[1]+f0.z*wk[2]+f0.w*wk[3]
                    + f1.x*wk[4]+f1.y*wk[5]+f1.z*wk[6]+f1.w*wk[7];
        }
    }
    int nb = bt*VV;
    #pragma unroll
    for (int j = 0; j < 12; j++)
        ybf[(size_t)(nb + vv*12 + j)*256 + 64 + o] = f2bf(acc[j]);
}

// ---------------- LN2 fused: outt -> xn bf16 ----------------
__global__ __launch_bounds__(256) void ln2xn(const float* __restrict__ outt,
        const float* __restrict__ g, const float* __restrict__ bb, unsigned short* __restrict__ xn){
    int n = blockIdx.x*4 + (threadIdx.x >> 6);
    int lane = threadIdx.x & 63;
    const float* row = outt + (size_t)n*256;
    float4 v = *(const float4*)(row + lane*4);
    float s = v.x+v.y+v.z+v.w;
    float ss = v.x*v.x+v.y*v.y+v.z*v.z+v.w*v.w;
    for (int off = 32; off; off >>= 1){ s += __shfl_xor(s, off); ss += __shfl_xor(ss, off); }
    float m = s*(1.0f/256), rs = rsqrtf(ss*(1.0f/256) - m*m + LNE);
    float4 g4 = *(const float4*)(g + lane*4);
    float4 b4 = *(const float4*)(bb + lane*4);
    ushort4 u;
    u.x = f2bf((v.x-m)*rs*g4.x + b4.x);
    u.y = f2bf((v.y-m)*rs*g4.y + b4.y);
    u.z = f2bf((v.z-m)*rs*g4.z + b4.z);
    u.w = f2bf((v.w-m)*rs*g4.w + b4.w);
    *(ushort4*)(xn + (size_t)n*256 + lane*4) = u;
}

extern "C" void kernel_launch(void* const* d_in, const int* in_sizes, int n_in,
                              void* d_out, int out_size, void* d_ws, size_t ws_size,
                              hipStream_t stream){
    const float* input   = (const float*)d_in[0];
    const float* n1g     = (const float*)d_in[1];
    const float* n1b     = (const float*)d_in[2];
    const float* map_w   = (const float*)d_in[3];
    const float* map_b   = (const float*)d_in[4];
    const float* gconv   = (const float*)d_in[5];
    const float* tconv_w = (const float*)d_in[6];
    const float* tconv_b = (const float*)d_in[7];
    const float* qkv_w0  = (const float*)d_in[8];
    const float* qkv_b0  = (const float*)d_in[9];
    const float* aproj_w0= (const float*)d_in[10];
    const float* aproj_b0= (const float*)d_in[11];
    const float* tcl_w0  = (const float*)d_in[12];
    const float* tcl_b0  = (const float*)d_in[13];
    const float* qkv_w1  = (const float*)d_in[14];
    const float* qkv_b1  = (const float*)d_in[15];
    const float* aproj_w1= (const float*)d_in[16];
    const float* aproj_b1= (const float*)d_in[17];
    const float* tcl_w1  = (const float*)d_in[18];
    const float* tcl_b1  = (const float*)d_in[19];
    const float* proj_w  = (const float*)d_in[20];
    const float* proj_b  = (const float*)d_in[21];
    const float* n2g     = (const float*)d_in[22];
    const float* n2b     = (const float*)d_in[23];
    const float* mlp_w1  = (const float*)d_in[24];
    const float* mlp_b1  = (const float*)d_in[25];
    const float* mlp_w2  = (const float*)d_in[26];
    const float* mlp_b2  = (const float*)d_in[27];

    const size_t Nt = NTOK;
    size_t need = ((size_t)896*Nt + 18432) * sizeof(float)
                + ((size_t)2*65536 + 2*262144 + 2*61440) * sizeof(unsigned short);
    if (ws_size < need) return;

    float* ws   = (float*)d_ws;
    float* outt = ws;                              // 256 Nt f32
    float* f    = outt + (size_t)256*Nt;           // 256 Nt f32
    unsigned short* a0p = (unsigned short*)(f + (size_t)256*Nt);  // padded attn out (bf16)
    float* wpad = (float*)a0p + (size_t)192*Nt;    // keeps h span layout
    unsigned short* A1 = (unsigned short*)(wpad + (size_t)64*Nt);
    float* gct  = (float*)(A1 + (size_t)256*Nt);
    unsigned short* mapT  = (unsigned short*)(gct + 18432);
    unsigned short* projT = mapT + 65536;
    unsigned short* w1T   = projT + 65536;
    unsigned short* w2T   = w1T + 262144;
    unsigned short* tclT0 = w2T + 262144;
    unsigned short* tclT1 = tclT0 + 61440;

    unsigned short* h   = (unsigned short*)f;      // bf16 N x 1024, spans f+a0p+wpad
    unsigned short* xn  = A1;
    unsigned short* ybf = (unsigned short*)d_out;  // bf16 N x 256 scratch
    float* dout = (float*)d_out;

    prep_weights<<<256, 256, 0, stream>>>(gconv, tcl_w0, tcl_w1, map_w, proj_w, mlp_w1, mlp_w2,
                                          gct, mapT, projT, w1T, w2T, tclT0, tclT1);
    xpose_ln1<<<NB*TT, 256, 0, stream>>>(input, n1g, n1b, A1);
    mfma_gemm<256,0><<<dim3(1024,2), 256, 0, stream>>>(A1, mapT, map_b, nullptr, f, nullptr, 256);
    hipMemsetAsync(a0p, 0, A0P_USH*sizeof(unsigned short), stream);
    attn_fused<<<NB*TT, 192, 0, stream>>>(f, 128, qkv_w0, qkv_b0, aproj_w0, aproj_b0, a0p);
    tcl_mfma<<<NTOK/192, 256, 0, stream>>>(a0p, tclT0, tcl_b0, ybf, 128);
    attn_fused<<<NB*TT, 192, 0, stream>>>(f, 192, qkv_w1, qkv_b1, aproj_w1, aproj_b1, a0p);
    tcl_mfma<<<NTOK/192, 256, 0, stream>>>(a0p, tclT1, tcl_b1, ybf, 192);
    y0_kernel<<<NB*TT, 256, 0, stream>>>(f, gct, ybf);
    y1_kernel<<<NB*TT, 256, 0, stream>>>(f, tconv_w, tconv_b, ybf);
    mfma_gemm<256,1><<<dim3(1024,2), 256, 0, stream>>>(ybf, projT, proj_b, input, outt, nullptr, 256);
    ln2xn<<<NTOK/4, 256, 0, stream>>>(outt, n2g, n2b, xn);
    mfma_gemm<256,2><<<dim3(1024,8), 256, 0, stream>>>(xn, w1T, mlp_b1, nullptr, nullptr, h, 1024);
    mfma_gemm<1024,3><<<dim3(1024,2), 256, 0, stream>>>(h, w2T, mlp_b2, outt, dout, nullptr, 256);
}

// Round 4
// 730.289 us; speedup vs baseline: 5.2861x; 1.3267x over previous
//
#include <hip/hip_runtime.h>
#include <hip/hip_bf16.h>
#include <math.h>

#define NB 32
#define CC 256
#define TT 64
#define VV 48
#define NTOK (NB*TT*VV)   // 98304
#define LNE 1e-5f
// padded attention-output layout: per batch 4*48 zero rows + 64*48 data rows (192 cols)
#define PROWS 3264        // (4+64)*48
#define A0P_USH ((size_t)NB*PROWS*192)

typedef __attribute__((ext_vector_type(8))) __bf16 bf16x8;
typedef __attribute__((ext_vector_type(4))) float f32x4;

__device__ inline float bfbits2f(unsigned int bits){
    union{unsigned int u; float f;} c; c.u = bits<<16; return c.f;
}
__device__ inline unsigned short f2bf(float x){
    union{float f; unsigned int u;} c; c.f = x;
    unsigned int r = (c.u + 0x7fffu + ((c.u>>16)&1u)) >> 16;
    return (unsigned short)r;
}
__device__ __forceinline__ void unpk8(uint4 u, float* d){
    d[0]=bfbits2f(u.x&0xffffu); d[1]=bfbits2f(u.x>>16);
    d[2]=bfbits2f(u.y&0xffffu); d[3]=bfbits2f(u.y>>16);
    d[4]=bfbits2f(u.z&0xffffu); d[5]=bfbits2f(u.z>>16);
    d[6]=bfbits2f(u.w&0xffffu); d[7]=bfbits2f(u.w>>16);
}

// ---------------- weight prep ----------------
__global__ void prep_weights(const float* gconv, const float* tcl0, const float* tcl1,
                             const float* map_w, const float* proj_w,
                             const float* mlp_w1, const float* mlp_w2,
                             const float* qkv_w0, const float* qkv_w1,
                             const float* aproj_w0, const float* aproj_w1,
                             float* gct,
                             unsigned short* mapT, unsigned short* projT,
                             unsigned short* w1T, unsigned short* w2T,
                             unsigned short* tclT0, unsigned short* tclT1,
                             unsigned short* qkvT, unsigned short* aprojT){
    int tid = blockIdx.x*blockDim.x + threadIdx.x;
    int stride = gridDim.x*blockDim.x;
    for (int i = tid; i < 8*48*48; i += stride){
        int g = i/(48*48); int r = i%(48*48); int u = r/48; int v = r%48;
        gct[i] = gconv[(g*48+v)*48+u];
    }
    // tclT[o][kh*192+c] = tcl[(o*192+c)*5+kh]   (64 x 960)
    for (int i = tid; i < 64*960; i += stride){
        int o = i/960, col = i%960, kh = col/192, c = col%192;
        tclT0[i] = f2bf(tcl0[(o*192+c)*5+kh]);
        tclT1[i] = f2bf(tcl1[(o*192+c)*5+kh]);
    }
    // mapT[n][k] = map_w[k][n]  (256x256)
    for (int i = tid; i < 65536; i += stride){
        int n = i>>8, k = i&255;
        mapT[i] = f2bf(map_w[k*256+n]);
        projT[i] = f2bf(proj_w[k*256+n]);
    }
    for (int i = tid; i < 262144; i += stride){
        int n = i>>8, k = i&255;
        w1T[i] = f2bf(mlp_w1[k*1024+n]);
    }
    for (int i = tid; i < 262144; i += stride){
        int n = i>>10, k = i&1023;
        w2T[i] = f2bf(mlp_w2[k*256+n]);
    }
    // qkvT/aprojT [br][n][k] = w[k*192+n], n<192, k<64
    for (int i = tid; i < 12288; i += stride){
        int n = i/64, k = i%64;
        qkvT[i]          = f2bf(qkv_w0[k*192+n]);
        qkvT[12288+i]    = f2bf(qkv_w1[k*192+n]);
        aprojT[i]        = f2bf(aproj_w0[k*192+n]);
        aprojT[12288+i]  = f2bf(aproj_w1[k*192+n]);
    }
}

// ---------------- LN1 + transpose -> A1 bf16 [N][256] ----------------
__global__ __launch_bounds__(256) void xpose_ln1(const float* __restrict__ x,
        const float* __restrict__ g, const float* __restrict__ bb,
        unsigned short* __restrict__ A1){
    int bt = blockIdx.x; int b = bt/TT, t = bt%TT;
    __shared__ float X[48*257];
    __shared__ float S[4][48], SS[4][48], sm[48], sv[48];
    int tid = threadIdx.x;
    const float* xb = x + (size_t)b*256*3072 + (size_t)t*48;
    for (int it = 0; it < 12; it++){
        int idx = it*256 + tid;
        int c = idx/12, q = idx%12;
        float4 v = *(const float4*)(xb + (size_t)c*3072 + q*4);
        X[(q*4+0)*257 + c] = v.x;
        X[(q*4+1)*257 + c] = v.y;
        X[(q*4+2)*257 + c] = v.z;
        X[(q*4+3)*257 + c] = v.w;
    }
    __syncthreads();
    if (tid < 192){
        int v = tid % 48, w = tid / 48;
        float s = 0.f, ss = 0.f;
        for (int c = w*64; c < w*64+64; c++){
            float val = X[v*257 + c];
            s += val; ss += val*val;
        }
        S[w][v] = s; SS[w][v] = ss;
    }
    __syncthreads();
    if (tid < 48){
        float s = S[0][tid]+S[1][tid]+S[2][tid]+S[3][tid];
        float q = SS[0][tid]+SS[1][tid]+SS[2][tid]+SS[3][tid];
        float m = s*(1.f/256);
        sm[tid] = m; sv[tid] = rsqrtf(q*(1.f/256) - m*m + LNE);
    }
    __syncthreads();
    int nb = bt*48;
    for (int it = 0; it < 12; it++){
        int idx = it*256 + tid;
        int v = idx>>6, cq = idx&63;
        float m = sm[v], rs = sv[v];
        float4 g4 = *(const float4*)(g + cq*4);
        float4 b4 = *(const float4*)(bb + cq*4);
        ushort4 u;
        u.x = f2bf((X[v*257 + cq*4+0]-m)*rs*g4.x + b4.x);
        u.y = f2bf((X[v*257 + cq*4+1]-m)*rs*g4.y + b4.y);
        u.z = f2bf((X[v*257 + cq*4+2]-m)*rs*g4.z + b4.z);
        u.w = f2bf((X[v*257 + cq*4+3]-m)*rs*g4.w + b4.w);
        *(ushort4*)(A1 + (size_t)(nb+v)*256 + cq*4) = u;
    }
}

// ---------------- swizzled staging: rows x 64 bf16 (128B/row in LDS) ----------------
__device__ __forceinline__ void stage_swz(const char* src, size_t rowbytes, char* lds,
                                          int nchunks, int tid){
    for (int c = tid; c < nchunks; c += 256){
        int p = c << 4;
        int r = p >> 7;
        int kl = (p & 127) ^ ((r & 7) << 4);
        __builtin_amdgcn_global_load_lds(
            (const __attribute__((address_space(1))) unsigned int*)(src + (size_t)r*rowbytes + kl),
            (__attribute__((address_space(3))) unsigned int*)(lds + p),
            16, 0, 0);
    }
}

__device__ __forceinline__ bf16x8 frag_ld(const char* lds, int R, int kb){
    return *(const bf16x8*)(lds + R*128 + (kb ^ ((R & 7) << 4)));
}

// ---------------- MFMA GEMM: BM=96, BN=128, BK=64, 4 waves(2x2) ----------------
// EPI 1: outF(outt) = acc + bias + skip(extra=input NCHW), via Tt transpose
// EPI 2: outH = bf16(gelu(acc + bias))
// EPI 3: outF(dout NCHW) = acc + bias + extra(outt), transposed store
// EPI 4: outH = bf16(acc + bias)
template<int KTOT, int EPI>
__global__ __launch_bounds__(256) void mfma_gemm(
    const unsigned short* __restrict__ A, const unsigned short* __restrict__ BT,
    const float* __restrict__ bias, const float* __restrict__ extra,
    float* __restrict__ outF, unsigned short* __restrict__ outH, int ncols){

    __shared__ __align__(16) char smem[(EPI==1||EPI==3) ? 51200 : 28672];
    char* ldsA = smem;
    char* ldsB = smem + 96*128;
    int tid = threadIdx.x, lane = tid & 63;
    int wid = tid >> 6, wm = wid >> 1, wn = wid & 1;
    int l15 = lane & 15, lq = lane >> 4;
    int m0 = blockIdx.x * 96, n0 = blockIdx.y * 128;
    const size_t arb = KTOT*2, brb = KTOT*2;

    f32x4 acc[3][4];
    #pragma unroll
    for (int i = 0; i < 3; i++)
        #pragma unroll
        for (int j = 0; j < 4; j++){ f32x4 z = {0.f,0.f,0.f,0.f}; acc[i][j] = z; }

    for (int kt = 0; kt < KTOT/64; kt++){
        const char* As = (const char*)A + (size_t)m0*arb + kt*128;
        const char* Bs = (const char*)BT + (size_t)n0*brb + kt*128;
        stage_swz(As, arb, ldsA, 96*8, tid);
        stage_swz(Bs, brb, ldsB, 128*8, tid);
        __syncthreads();
        #pragma unroll
        for (int ks = 0; ks < 2; ks++){
            bf16x8 a[3], b[4];
            int kb = ks*64 + lq*16;
            #pragma unroll
            for (int mf = 0; mf < 3; mf++) a[mf] = frag_ld(ldsA, wm*48 + mf*16 + l15, kb);
            #pragma unroll
            for (int nf = 0; nf < 4; nf++) b[nf] = frag_ld(ldsB, wn*64 + nf*16 + l15, kb);
            #pragma unroll
            for (int mf = 0; mf < 3; mf++)
                #pragma unroll
                for (int nf = 0; nf < 4; nf++)
                    acc[mf][nf] = __builtin_amdgcn_mfma_f32_16x16x32_bf16(a[mf], b[nf], acc[mf][nf], 0, 0, 0);
        }
        __syncthreads();
    }

    if constexpr (EPI == 2 || EPI == 4){
        #pragma unroll
        for (int nf = 0; nf < 4; nf++){
            int cl = n0 + wn*64 + nf*16 + l15;
            float bb = bias[cl];
            #pragma unroll
            for (int mf = 0; mf < 3; mf++){
                int tl = m0 + wm*48 + mf*16 + lq*4;
                f32x4 v = acc[mf][nf];
                #pragma unroll
                for (int r = 0; r < 4; r++){
                    float t0 = v[r] + bb;
                    if constexpr (EPI == 2)
                        t0 = 0.5f*t0*(1.0f + erff(t0*0.70710678118f));
                    outH[(size_t)(tl+r)*ncols + cl] = f2bf(t0);
                }
            }
        }
    }
    if constexpr (EPI == 1){
        float* Tt = (float*)smem;  // [128][100]
        #pragma unroll
        for (int nf = 0; nf < 4; nf++){
            int cl = wn*64 + nf*16 + l15;
            float bb = bias[n0 + cl];
            #pragma unroll
            for (int mf = 0; mf < 3; mf++){
                int tl = wm*48 + mf*16 + lq*4;
                f32x4 v = acc[mf][nf];
                #pragma unroll
                for (int r = 0; r < 4; r++)
                    Tt[cl*100 + tl + r] = v[r] + bb;
            }
        }
        __syncthreads();
        {
            int btl = tid >> 7, c = tid & 127;
            int gtok = m0 + btl*48;
            int bg = gtok/3072, t = (gtok%3072)/48;
            const float* sp = extra + ((size_t)(bg*256 + n0 + c)*64 + t)*48;
            float* tr = Tt + c*100 + btl*48;
            #pragma unroll
            for (int j = 0; j < 12; j++){
                float4 s4 = *(const float4*)(sp + j*4);
                float4 t4 = *(float4*)(tr + j*4);
                t4.x += s4.x; t4.y += s4.y; t4.z += s4.z; t4.w += s4.w;
                *(float4*)(tr + j*4) = t4;
            }
        }
        __syncthreads();
        for (int it = 0; it < 12; it++){
            int idx = it*256 + tid;
            int cq = idx/96, nl = idx%96;
            float4 o;
            o.x = Tt[(cq*4+0)*100 + nl];
            o.y = Tt[(cq*4+1)*100 + nl];
            o.z = Tt[(cq*4+2)*100 + nl];
            o.w = Tt[(cq*4+3)*100 + nl];
            *(float4*)(outF + (size_t)(m0+nl)*256 + n0 + cq*4) = o;
        }
    }
    if constexpr (EPI == 3){
        float* Tt = (float*)smem;  // [128][100]
        #pragma unroll
        for (int nf = 0; nf < 4; nf++){
            int cl = wn*64 + nf*16 + l15;
            float bb = bias[n0 + cl];
            #pragma unroll
            for (int mf = 0; mf < 3; mf++){
                int tl = wm*48 + mf*16 + lq*4;
                f32x4 v = acc[mf][nf];
                #pragma unroll
                for (int r = 0; r < 4; r++){
                    float resid = extra[(size_t)(m0+tl+r)*256 + n0 + cl];
                    Tt[cl*100 + tl + r] = v[r] + bb + resid;
                }
            }
        }
        __syncthreads();
        {
            int btl = tid >> 7, c = tid & 127;
            int gtok = m0 + btl*48;
            int bg = gtok/3072, t = (gtok%3072)/48;
            float* dst = outF + ((size_t)(bg*256 + n0 + c)*64 + t)*48;
            const float* tr = Tt + c*100 + btl*48;
            #pragma unroll
            for (int j = 0; j < 12; j++)
                *(float4*)(dst + j*4) = *(const float4*)(tr + j*4);
        }
    }
}

// ---------------- K=64 MFMA GEMM: BM=96, BN=192, 4 waves (2x2: 48r x 96c) ----------------
// EPI 0: out = qkvbuf flat [token][192] bf16 (+bias)
// EPI 1: out = a0p padded rows bf16 (+bias)
template<int EPI>
__global__ __launch_bounds__(256) void gemm_k64(
    const unsigned short* __restrict__ A, int arb,
    const unsigned short* __restrict__ BT,
    const float* __restrict__ bias,
    unsigned short* __restrict__ out){
    __shared__ __align__(16) char smem[96*128 + 192*128];
    char* ldsA = smem;
    char* ldsB = smem + 96*128;
    int tid = threadIdx.x, lane = tid & 63;
    int wid = tid >> 6, wm = wid >> 1, wn = wid & 1;
    int l15 = lane & 15, lq = lane >> 4;
    int m0 = blockIdx.x * 96;

    stage_swz((const char*)A + (size_t)m0*arb, arb, ldsA, 96*8, tid);
    stage_swz((const char*)BT, 128, ldsB, 192*8, tid);
    __syncthreads();

    f32x4 acc[3][6];
    #pragma unroll
    for (int i = 0; i < 3; i++)
        #pragma unroll
        for (int j = 0; j < 6; j++){ f32x4 z = {0.f,0.f,0.f,0.f}; acc[i][j] = z; }

    #pragma unroll
    for (int ks = 0; ks < 2; ks++){
        bf16x8 a[3], b[6];
        int kb = ks*64 + lq*16;
        #pragma unroll
        for (int mf = 0; mf < 3; mf++) a[mf] = frag_ld(ldsA, wm*48 + mf*16 + l15, kb);
        #pragma unroll
        for (int nf = 0; nf < 6; nf++) b[nf] = frag_ld(ldsB, wn*96 + nf*16 + l15, kb);
        #pragma unroll
        for (int mf = 0; mf < 3; mf++)
            #pragma unroll
            for (int nf = 0; nf < 6; nf++)
                acc[mf][nf] = __builtin_amdgcn_mfma_f32_16x16x32_bf16(a[mf], b[nf], acc[mf][nf], 0, 0, 0);
    }

    size_t row0;
    if constexpr (EPI == 0) row0 = (size_t)m0;
    else {
        int b = m0/3072;
        row0 = (size_t)b*PROWS + 192 + (m0 - b*3072);
    }
    #pragma unroll
    for (int nf = 0; nf < 6; nf++){
        int col = wn*96 + nf*16 + l15;
        float bb = bias[col];
        #pragma unroll
        for (int mf = 0; mf < 3; mf++){
            size_t rr = row0 + wm*48 + mf*16 + lq*4;
            f32x4 v = acc[mf][nf];
            #pragma unroll
            for (int r = 0; r < 4; r++)
                out[(rr+r)*192 + col] = f2bf(v[r] + bb);
        }
    }
}

// ---------------- windowed attention: per (window, branch), fp32 softmax ----------------
__global__ __launch_bounds__(192) void attn_win(
        const unsigned short* __restrict__ qkvbuf,   // [2][Nt][192]
        unsigned short* __restrict__ attnout){       // [2][Nt][64]
    int win = blockIdx.x, br = blockIdx.y;
    size_t base = (size_t)br*NTOK + (size_t)win*48;
    __shared__ float Q[48*196];
    int tid = threadIdx.x;
    const unsigned short* src = qkvbuf + base*192;
    for (int i = 0; i < 6; i++){
        int ch = i*192 + tid;        // 1152 chunks of 8
        int v = ch/24, c8 = ch%24;
        uint4 u = *(const uint4*)(src + (size_t)v*192 + c8*8);
        unpk8(u, &Q[v*196 + c8*8]);
    }
    __syncthreads();
    int u = tid & 15, gh = tid >> 4, g = gh >> 2, h = gh & 3;
    int ru = g*16 + u;
    float qreg[16];
    #pragma unroll
    for (int d = 0; d < 16; d++) qreg[d] = Q[ru*196 + h*16 + d];
    float sc[16]; float mx = -1e30f;
    #pragma unroll
    for (int w = 0; w < 16; w++){
        float s = 0.f;
        #pragma unroll
        for (int d = 0; d < 16; d++) s += qreg[d]*Q[(g*16+w)*196 + 64 + h*16 + d];
        s *= 0.5f; sc[w] = s; mx = fmaxf(mx, s);
    }
    float sum = 0.f;
    #pragma unroll
    for (int w = 0; w < 16; w++){ sc[w] = expf(sc[w]-mx); sum += sc[w]; }
    float inv = 1.0f/sum;
    unsigned int w32[8];
    #pragma unroll
    for (int dp = 0; dp < 8; dp++){
        float o0 = 0.f, o1 = 0.f;
        #pragma unroll
        for (int w = 0; w < 16; w++){
            float p = sc[w];
            o0 += p*Q[(g*16+w)*196 + 128 + h*16 + dp*2];
            o1 += p*Q[(g*16+w)*196 + 128 + h*16 + dp*2+1];
        }
        w32[dp] = (unsigned int)f2bf(o0*inv) | ((unsigned int)f2bf(o1*inv) << 16);
    }
    unsigned short* dst = attnout + (base + ru)*64 + h*16;
    uint4 q0; q0.x=w32[0]; q0.y=w32[1]; q0.z=w32[2]; q0.w=w32[3];
    uint4 q1; q1.x=w32[4]; q1.y=w32[5]; q1.z=w32[6]; q1.w=w32[7];
    *(uint4*)(dst)   = q0;
    *(uint4*)(dst+8) = q1;
}

// ---------------- tcl as MFMA GEMM: K=960 via 5 shifted taps, BM=192, BN=64 ----------------
__global__ __launch_bounds__(256) void tcl_mfma(const unsigned short* __restrict__ A0p,
        const unsigned short* __restrict__ BT, const float* __restrict__ tb,
        unsigned short* __restrict__ ybf, int outoff){
    __shared__ __align__(16) char smem[192*128 + 64*128];
    char* ldsA = smem;
    char* ldsB = smem + 192*128;
    int tid = threadIdx.x, lane = tid & 63;
    int wid = tid >> 6;
    int l15 = lane & 15, lq = lane >> 4;
    int m0 = blockIdx.x * 192;
    int b = m0 / 3072;
    long brow0 = (long)b*PROWS + 192 + (m0 - b*3072);

    f32x4 acc[3][4];
    #pragma unroll
    for (int i = 0; i < 3; i++)
        #pragma unroll
        for (int j = 0; j < 4; j++){ f32x4 z = {0.f,0.f,0.f,0.f}; acc[i][j] = z; }

    for (int kh = 0; kh < 5; kh++){
        long rowA = brow0 + (long)(kh-4)*48;
        for (int kc3 = 0; kc3 < 3; kc3++){
            int kt = kh*3 + kc3;
            const char* As = (const char*)A0p + rowA*384 + kc3*128;
            const char* Bs = (const char*)BT + kt*128;
            stage_swz(As, 384, ldsA, 192*8, tid);
            stage_swz(Bs, 1920, ldsB, 64*8, tid);
            __syncthreads();
            #pragma unroll
            for (int ks = 0; ks < 2; ks++){
                bf16x8 a[3], bb[4];
                int kb = ks*64 + lq*16;
                #pragma unroll
                for (int mf = 0; mf < 3; mf++) a[mf] = frag_ld(ldsA, wid*48 + mf*16 + l15, kb);
                #pragma unroll
                for (int nf = 0; nf < 4; nf++) bb[nf] = frag_ld(ldsB, nf*16 + l15, kb);
                #pragma unroll
                for (int mf = 0; mf < 3; mf++)
                    #pragma unroll
                    for (int nf = 0; nf < 4; nf++)
                        acc[mf][nf] = __builtin_amdgcn_mfma_f32_16x16x32_bf16(a[mf], bb[nf], acc[mf][nf], 0, 0, 0);
            }
            __syncthreads();
        }
    }
    #pragma unroll
    for (int nf = 0; nf < 4; nf++){
        int col = nf*16 + l15;
        float bb = tb[col];
        #pragma unroll
        for (int mf = 0; mf < 3; mf++){
            int tok = m0 + wid*48 + mf*16 + lq*4;
            f32x4 v = acc[mf][nf];
            #pragma unroll
            for (int r = 0; r < 4; r++)
                ybf[(size_t)(tok+r)*256 + outoff + col] = f2bf(v[r] + bb);
        }
    }
}

// ---------------- y0: grouped V-mix -> ybf cols 0..63 (bf16 in/out) ----------------
__global__ __launch_bounds__(256) void y0_kernel(const unsigned short* __restrict__ fbf,
        const float* __restrict__ gct, unsigned short* __restrict__ ybf){
    int bt = blockIdx.x; int nb = bt*VV;
    __shared__ float X[48*68];
    for (int it = 0; it < 2; it++){
        int idx = it*256 + threadIdx.x;    // 384 = 48 x 8 chunks
        if (idx < 384){
            int v = idx >> 3, c8 = idx & 7;
            uint4 u = *(const uint4*)(fbf + (size_t)(nb+v)*256 + c8*8);
            unpk8(u, &X[v*68 + c8*8]);
        }
    }
    __syncthreads();
    int c = threadIdx.x % 64, vv = threadIdx.x / 64;
    int g = c >> 3;
    float acc[12] = {};
    for (int u = 0; u < 48; u++){
        float xv = X[u*68 + c];
        const float* gr = gct + (size_t)(g*48+u)*48 + vv*12;
        float4 g0 = *(const float4*)(gr);
        float4 g1 = *(const float4*)(gr+4);
        float4 g2 = *(const float4*)(gr+8);
        acc[0]+=xv*g0.x; acc[1]+=xv*g0.y; acc[2]+=xv*g0.z;  acc[3]+=xv*g0.w;
        acc[4]+=xv*g1.x; acc[5]+=xv*g1.y; acc[6]+=xv*g1.z;  acc[7]+=xv*g1.w;
        acc[8]+=xv*g2.x; acc[9]+=xv*g2.y; acc[10]+=xv*g2.z; acc[11]+=xv*g2.w;
    }
    #pragma unroll
    for (int j = 0; j < 12; j++)
        ybf[(size_t)(nb + vv*12 + j)*256 + c] = f2bf(acc[j]);
}

// ---------------- y1: grouped temporal conv (k=7) -> ybf cols 64..127 ----------------
__global__ __launch_bounds__(256) void y1_kernel(const unsigned short* __restrict__ fbf,
        const float* __restrict__ tw, const float* __restrict__ tb, unsigned short* __restrict__ ybf){
    int bt = blockIdx.x; int b = bt/TT, t = bt%TT;
    int o = threadIdx.x % 64, vv = threadIdx.x / 64;
    int g = o >> 3;
    float bv = tb[o];
    float acc[12];
    #pragma unroll
    for (int j = 0; j < 12; j++) acc[j] = bv;
    for (int kh = 0; kh < 7; kh++){
        int tt = t + kh - 3;
        if (tt < 0 || tt >= TT) continue;
        float wk[8];
        #pragma unroll
        for (int ci = 0; ci < 8; ci++) wk[ci] = tw[(o*8+ci)*7 + kh];
        int nb2 = (b*TT+tt)*VV;
        #pragma unroll
        for (int j = 0; j < 12; j++){
            uint4 u = *(const uint4*)(fbf + (size_t)(nb2 + vv*12 + j)*256 + 64 + g*8);
            float fv[8]; unpk8(u, fv);
            acc[j] += fv[0]*wk[0]+fv[1]*wk[1]+fv[2]*wk[2]+fv[3]*wk[3]
                    + fv[4]*wk[4]+fv[5]*wk[5]+fv[6]*wk[6]+fv[7]*wk[7];
        }
    }
    int nb = bt*VV;
    #pragma unroll
    for (int j = 0; j < 12; j++)
        ybf[(size_t)(nb + vv*12 + j)*256 + 64 + o] = f2bf(acc[j]);
}

// ---------------- LN2 fused: outt -> xn bf16 ----------------
__global__ __launch_bounds__(256) void ln2xn(const float* __restrict__ outt,
        const float* __restrict__ g, const float* __restrict__ bb, unsigned short* __restrict__ xn){
    int n = blockIdx.x*4 + (threadIdx.x >> 6);
    int lane = threadIdx.x & 63;
    const float* row = outt + (size_t)n*256;
    float4 v = *(const float4*)(row + lane*4);
    float s = v.x+v.y+v.z+v.w;
    float ss = v.x*v.x+v.y*v.y+v.z*v.z+v.w*v.w;
    for (int off = 32; off; off >>= 1){ s += __shfl_xor(s, off); ss += __shfl_xor(ss, off); }
    float m = s*(1.0f/256), rs = rsqrtf(ss*(1.0f/256) - m*m + LNE);
    float4 g4 = *(const float4*)(g + lane*4);
    float4 b4 = *(const float4*)(bb + lane*4);
    ushort4 u;
    u.x = f2bf((v.x-m)*rs*g4.x + b4.x);
    u.y = f2bf((v.y-m)*rs*g4.y + b4.y);
    u.z = f2bf((v.z-m)*rs*g4.z + b4.z);
    u.w = f2bf((v.w-m)*rs*g4.w + b4.w);
    *(ushort4*)(xn + (size_t)n*256 + lane*4) = u;
}

extern "C" void kernel_launch(void* const* d_in, const int* in_sizes, int n_in,
                              void* d_out, int out_size, void* d_ws, size_t ws_size,
                              hipStream_t stream){
    const float* input   = (const float*)d_in[0];
    const float* n1g     = (const float*)d_in[1];
    const float* n1b     = (const float*)d_in[2];
    const float* map_w   = (const float*)d_in[3];
    const float* map_b   = (const float*)d_in[4];
    const float* gconv   = (const float*)d_in[5];
    const float* tconv_w = (const float*)d_in[6];
    const float* tconv_b = (const float*)d_in[7];
    const float* qkv_w0  = (const float*)d_in[8];
    const float* qkv_b0  = (const float*)d_in[9];
    const float* aproj_w0= (const float*)d_in[10];
    const float* aproj_b0= (const float*)d_in[11];
    const float* tcl_w0  = (const float*)d_in[12];
    const float* tcl_b0  = (const float*)d_in[13];
    const float* qkv_w1  = (const float*)d_in[14];
    const float* qkv_b1  = (const float*)d_in[15];
    const float* aproj_w1= (const float*)d_in[16];
    const float* aproj_b1= (const float*)d_in[17];
    const float* tcl_w1  = (const float*)d_in[18];
    const float* tcl_b1  = (const float*)d_in[19];
    const float* proj_w  = (const float*)d_in[20];
    const float* proj_b  = (const float*)d_in[21];
    const float* n2g     = (const float*)d_in[22];
    const float* n2b     = (const float*)d_in[23];
    const float* mlp_w1  = (const float*)d_in[24];
    const float* mlp_b1  = (const float*)d_in[25];
    const float* mlp_w2  = (const float*)d_in[26];
    const float* mlp_b2  = (const float*)d_in[27];

    const size_t Nt = NTOK;
    if (ws_size < 354050048ull) return;

    char* base = (char*)d_ws;
    float* outt            = (float*)base;                           // 100,663,296
    unsigned short* fbf    = (unsigned short*)(base + 100663296);    //  50,331,648
    unsigned short* a0p    = (unsigned short*)(base + 150994944);    //  40,108,032
    unsigned short* qkvbuf = (unsigned short*)(base + 191102976);    //  75,497,472
    unsigned short* attnout= (unsigned short*)(base + 266600448);    //  25,165,824
    // pad 291,766,272 .. 301,989,888 (h overflow)
    unsigned short* A1     = (unsigned short*)(base + 301989888);    //  50,331,648
    char* wp = base + 352321536;
    float* gct            = (float*)wp;                 // 73,728
    unsigned short* mapT  = (unsigned short*)(wp + 73728);
    unsigned short* projT = mapT + 65536;
    unsigned short* w1T   = projT + 65536;
    unsigned short* w2T   = w1T + 262144;
    unsigned short* tclT0 = w2T + 262144;
    unsigned short* tclT1 = tclT0 + 61440;
    unsigned short* qkvT  = tclT1 + 61440;      // 2 x 12288
    unsigned short* aprojT= qkvT + 24576;       // 2 x 12288

    unsigned short* h   = fbf;                   // bf16 Nt x 1024: fbf..pad end (exact)
    unsigned short* xn  = A1;
    unsigned short* ybf = (unsigned short*)d_out;
    float* dout = (float*)d_out;

    prep_weights<<<256, 256, 0, stream>>>(gconv, tcl_w0, tcl_w1, map_w, proj_w, mlp_w1, mlp_w2,
                                          qkv_w0, qkv_w1, aproj_w0, aproj_w1,
                                          gct, mapT, projT, w1T, w2T, tclT0, tclT1, qkvT, aprojT);
    xpose_ln1<<<NB*TT, 256, 0, stream>>>(input, n1g, n1b, A1);
    mfma_gemm<256,4><<<dim3(1024,2), 256, 0, stream>>>(A1, mapT, map_b, nullptr, nullptr, fbf, 256);
    hipMemsetAsync(a0p, 0, A0P_USH*sizeof(unsigned short), stream);
    gemm_k64<0><<<1024, 256, 0, stream>>>(fbf + 128, 512, qkvT,         qkv_b0, qkvbuf);
    gemm_k64<0><<<1024, 256, 0, stream>>>(fbf + 192, 512, qkvT + 12288, qkv_b1, qkvbuf + (size_t)Nt*192);
    attn_win<<<dim3(2048,2), 192, 0, stream>>>(qkvbuf, attnout);
    y0_kernel<<<NB*TT, 256, 0, stream>>>(fbf, gct, ybf);
    y1_kernel<<<NB*TT, 256, 0, stream>>>(fbf, tconv_w, tconv_b, ybf);
    gemm_k64<1><<<1024, 256, 0, stream>>>(attnout,                 128, aprojT,         aproj_b0, a0p);
    tcl_mfma<<<NTOK/192, 256, 0, stream>>>(a0p, tclT0, tcl_b0, ybf, 128);
    gemm_k64<1><<<1024, 256, 0, stream>>>(attnout + (size_t)Nt*64, 128, aprojT + 12288, aproj_b1, a0p);
    tcl_mfma<<<NTOK/192, 256, 0, stream>>>(a0p, tclT1, tcl_b1, ybf, 192);
    mfma_gemm<256,1><<<dim3(1024,2), 256, 0, stream>>>(ybf, projT, proj_b, input, outt, nullptr, 256);
    ln2xn<<<NTOK/4, 256, 0, stream>>>(outt, n2g, n2b, xn);
    mfma_gemm<256,2><<<dim3(1024,8), 256, 0, stream>>>(xn, w1T, mlp_b1, nullptr, nullptr, h, 1024);
    mfma_gemm<1024,3><<<dim3(1024,2), 256, 0, stream>>>(h, w2T, mlp_b2, outt, dout, nullptr, 256);
}

// Round 5
// 699.708 us; speedup vs baseline: 5.5171x; 1.0437x over previous
//
#include <hip/hip_runtime.h>
#include <hip/hip_bf16.h>
#include <math.h>

#define NB 32
#define CC 256
#define TT 64
#define VV 48
#define NTOK (NB*TT*VV)   // 98304
#define LNE 1e-5f
// padded attention-output layout: per batch 4*48 zero rows + 64*48 data rows (192 cols)
#define PROWS 3264        // (4+64)*48
#define A0P_USH ((size_t)NB*PROWS*192)

typedef __attribute__((ext_vector_type(8))) __bf16 bf16x8;
typedef __attribute__((ext_vector_type(4))) float f32x4;

__device__ inline float bfbits2f(unsigned int bits){
    union{unsigned int u; float f;} c; c.u = bits<<16; return c.f;
}
__device__ inline unsigned short f2bf(float x){
    union{float f; unsigned int u;} c; c.f = x;
    unsigned int r = (c.u + 0x7fffu + ((c.u>>16)&1u)) >> 16;
    return (unsigned short)r;
}
__device__ __forceinline__ void unpk8(uint4 u, float* d){
    d[0]=bfbits2f(u.x&0xffffu); d[1]=bfbits2f(u.x>>16);
    d[2]=bfbits2f(u.y&0xffffu); d[3]=bfbits2f(u.y>>16);
    d[4]=bfbits2f(u.z&0xffffu); d[5]=bfbits2f(u.z>>16);
    d[6]=bfbits2f(u.w&0xffffu); d[7]=bfbits2f(u.w>>16);
}

// ---------------- weight prep ----------------
__global__ void prep_weights(const float* gconv, const float* tcl0, const float* tcl1,
                             const float* map_w, const float* proj_w,
                             const float* mlp_w1, const float* mlp_w2,
                             const float* qkv_w0, const float* qkv_w1,
                             const float* aproj_w0, const float* aproj_w1,
                             float* gct,
                             unsigned short* mapT, unsigned short* projT,
                             unsigned short* w1T, unsigned short* w2T,
                             unsigned short* tclT0, unsigned short* tclT1,
                             unsigned short* qkvT, unsigned short* aprojT){
    int tid = blockIdx.x*blockDim.x + threadIdx.x;
    int stride = gridDim.x*blockDim.x;
    for (int i = tid; i < 8*48*48; i += stride){
        int g = i/(48*48); int r = i%(48*48); int u = r/48; int v = r%48;
        gct[i] = gconv[(g*48+v)*48+u];
    }
    // tclT[o][kh*192+c] = tcl[(o*192+c)*5+kh]   (64 x 960)
    for (int i = tid; i < 64*960; i += stride){
        int o = i/960, col = i%960, kh = col/192, c = col%192;
        tclT0[i] = f2bf(tcl0[(o*192+c)*5+kh]);
        tclT1[i] = f2bf(tcl1[(o*192+c)*5+kh]);
    }
    // mapT[n][k] = map_w[k][n]  (256x256)
    for (int i = tid; i < 65536; i += stride){
        int n = i>>8, k = i&255;
        mapT[i] = f2bf(map_w[k*256+n]);
        projT[i] = f2bf(proj_w[k*256+n]);
    }
    for (int i = tid; i < 262144; i += stride){
        int n = i>>8, k = i&255;
        w1T[i] = f2bf(mlp_w1[k*1024+n]);
    }
    for (int i = tid; i < 262144; i += stride){
        int n = i>>10, k = i&1023;
        w2T[i] = f2bf(mlp_w2[k*256+n]);
    }
    // qkvT/aprojT [br][n][k] = w[k*192+n], n<192, k<64
    for (int i = tid; i < 12288; i += stride){
        int n = i/64, k = i%64;
        qkvT[i]          = f2bf(qkv_w0[k*192+n]);
        qkvT[12288+i]    = f2bf(qkv_w1[k*192+n]);
        aprojT[i]        = f2bf(aproj_w0[k*192+n]);
        aprojT[12288+i]  = f2bf(aproj_w1[k*192+n]);
    }
}

// ---------------- LN1 + transpose -> A1 bf16 [N][256] ----------------
__global__ __launch_bounds__(256) void xpose_ln1(const float* __restrict__ x,
        const float* __restrict__ g, const float* __restrict__ bb,
        unsigned short* __restrict__ A1){
    int bt = blockIdx.x; int b = bt/TT, t = bt%TT;
    __shared__ float X[48*257];
    __shared__ float S[4][48], SS[4][48], sm[48], sv[48];
    int tid = threadIdx.x;
    const float* xb = x + (size_t)b*256*3072 + (size_t)t*48;
    for (int it = 0; it < 12; it++){
        int idx = it*256 + tid;
        int c = idx/12, q = idx%12;
        float4 v = *(const float4*)(xb + (size_t)c*3072 + q*4);
        X[(q*4+0)*257 + c] = v.x;
        X[(q*4+1)*257 + c] = v.y;
        X[(q*4+2)*257 + c] = v.z;
        X[(q*4+3)*257 + c] = v.w;
    }
    __syncthreads();
    if (tid < 192){
        int v = tid % 48, w = tid / 48;
        float s = 0.f, ss = 0.f;
        for (int c = w*64; c < w*64+64; c++){
            float val = X[v*257 + c];
            s += val; ss += val*val;
        }
        S[w][v] = s; SS[w][v] = ss;
    }
    __syncthreads();
    if (tid < 48){
        float s = S[0][tid]+S[1][tid]+S[2][tid]+S[3][tid];
        float q = SS[0][tid]+SS[1][tid]+SS[2][tid]+SS[3][tid];
        float m = s*(1.f/256);
        sm[tid] = m; sv[tid] = rsqrtf(q*(1.f/256) - m*m + LNE);
    }
    __syncthreads();
    int nb = bt*48;
    for (int it = 0; it < 12; it++){
        int idx = it*256 + tid;
        int v = idx>>6, cq = idx&63;
        float m = sm[v], rs = sv[v];
        float4 g4 = *(const float4*)(g + cq*4);
        float4 b4 = *(const float4*)(bb + cq*4);
        ushort4 u;
        u.x = f2bf((X[v*257 + cq*4+0]-m)*rs*g4.x + b4.x);
        u.y = f2bf((X[v*257 + cq*4+1]-m)*rs*g4.y + b4.y);
        u.z = f2bf((X[v*257 + cq*4+2]-m)*rs*g4.z + b4.z);
        u.w = f2bf((X[v*257 + cq*4+3]-m)*rs*g4.w + b4.w);
        *(ushort4*)(A1 + (size_t)(nb+v)*256 + cq*4) = u;
    }
}

// ---------------- swizzled staging: rows x 64 bf16 (128B/row in LDS) ----------------
__device__ __forceinline__ void stage_swz(const char* src, size_t rowbytes, char* lds,
                                          int nchunks, int tid){
    for (int c = tid; c < nchunks; c += 256){
        int p = c << 4;
        int r = p >> 7;
        int kl = (p & 127) ^ ((r & 7) << 4);
        __builtin_amdgcn_global_load_lds(
            (const __attribute__((address_space(1))) unsigned int*)(src + (size_t)r*rowbytes + kl),
            (__attribute__((address_space(3))) unsigned int*)(lds + p),
            16, 0, 0);
    }
}

__device__ __forceinline__ bf16x8 frag_ld(const char* lds, int R, int kb){
    return *(const bf16x8*)(lds + R*128 + (kb ^ ((R & 7) << 4)));
}

// ---------------- MFMA GEMM: BM=96, BN template, BK=64, 4 waves(2x2) ----------------
// 1-D grid, XCD-bijective decode: wid = (bid&7)*(nwg/8) + (bid>>3); m = wid/nx, n = wid%nx
// EPI 1: outF(outt) = acc + bias + skip(extra=input NCHW), via Tt transpose
// EPI 2: outH = bf16(gelu(acc + bias))  [LDS-repacked 16B stores]
// EPI 3: outF(dout NCHW) = acc + bias + extra(outt), transposed store
// EPI 4: outH = bf16(acc + bias)        [LDS-repacked 16B stores]
template<int KTOT, int EPI, int BN>
__global__ __launch_bounds__(256) void mfma_gemm(
    const unsigned short* __restrict__ A, const unsigned short* __restrict__ BT,
    const float* __restrict__ bias, const float* __restrict__ extra,
    float* __restrict__ outF, unsigned short* __restrict__ outH, int ncols, int nx){

    constexpr int NF = BN/32;                 // frags per wave in N
    constexpr int STG = 96*128 + BN*128;
    constexpr int RPK = 96*BN*2;
    constexpr int SM = (EPI==1||EPI==3) ? 51200 : (STG > RPK ? STG : RPK);
    __shared__ __align__(16) char smem[SM];
    char* ldsA = smem;
    char* ldsB = smem + 96*128;
    int tid = threadIdx.x, lane = tid & 63;
    int wid = tid >> 6, wm = wid >> 1, wn = wid & 1;
    int l15 = lane & 15, lq = lane >> 4;
    int bid = blockIdx.x;
    int per = gridDim.x >> 3;
    int wkid = (bid & 7)*per + (bid >> 3);
    int m0 = (wkid / nx) * 96, n0 = (wkid % nx) * BN;
    const size_t arb = KTOT*2, brb = KTOT*2;

    f32x4 acc[3][NF];
    #pragma unroll
    for (int i = 0; i < 3; i++)
        #pragma unroll
        for (int j = 0; j < NF; j++){ f32x4 z = {0.f,0.f,0.f,0.f}; acc[i][j] = z; }

    for (int kt = 0; kt < KTOT/64; kt++){
        const char* As = (const char*)A + (size_t)m0*arb + kt*128;
        const char* Bs = (const char*)BT + (size_t)n0*brb + kt*128;
        stage_swz(As, arb, ldsA, 96*8, tid);
        stage_swz(Bs, brb, ldsB, BN*8, tid);
        __syncthreads();
        #pragma unroll
        for (int ks = 0; ks < 2; ks++){
            bf16x8 a[3], b[NF];
            int kb = ks*64 + lq*16;
            #pragma unroll
            for (int mf = 0; mf < 3; mf++) a[mf] = frag_ld(ldsA, wm*48 + mf*16 + l15, kb);
            #pragma unroll
            for (int nf = 0; nf < NF; nf++) b[nf] = frag_ld(ldsB, wn*(BN/2) + nf*16 + l15, kb);
            #pragma unroll
            for (int mf = 0; mf < 3; mf++)
                #pragma unroll
                for (int nf = 0; nf < NF; nf++)
                    acc[mf][nf] = __builtin_amdgcn_mfma_f32_16x16x32_bf16(a[mf], b[nf], acc[mf][nf], 0, 0, 0);
        }
        __syncthreads();
    }

    if constexpr (EPI == 2 || EPI == 4){
        unsigned short* Hs = (unsigned short*)smem;
        #pragma unroll
        for (int nf = 0; nf < NF; nf++){
            int col = wn*(BN/2) + nf*16 + l15;
            float bb = bias[n0 + col];
            #pragma unroll
            for (int mf = 0; mf < 3; mf++){
                int row = wm*48 + mf*16 + lq*4;
                f32x4 v = acc[mf][nf];
                #pragma unroll
                for (int r = 0; r < 4; r++){
                    float t0 = v[r] + bb;
                    if constexpr (EPI == 2)
                        t0 = 0.5f*t0*(1.0f + erff(t0*0.70710678118f));
                    Hs[(row+r)*BN + col] = f2bf(t0);
                }
            }
        }
        __syncthreads();
        constexpr int CHR = BN/8;
        for (int idx = tid; idx < 96*CHR; idx += 256){
            int row = idx/CHR, c8 = idx%CHR;
            *(uint4*)(outH + (size_t)(m0+row)*ncols + n0 + c8*8) =
                *(const uint4*)(Hs + row*BN + c8*8);
        }
    }
    if constexpr (EPI == 1){
        float* Tt = (float*)smem;  // [128][100]
        #pragma unroll
        for (int nf = 0; nf < NF; nf++){
            int cl = wn*(BN/2) + nf*16 + l15;
            float bb = bias[n0 + cl];
            #pragma unroll
            for (int mf = 0; mf < 3; mf++){
                int tl = wm*48 + mf*16 + lq*4;
                f32x4 v = acc[mf][nf];
                #pragma unroll
                for (int r = 0; r < 4; r++)
                    Tt[cl*100 + tl + r] = v[r] + bb;
            }
        }
        __syncthreads();
        {
            int btl = tid >> 7, c = tid & 127;
            int gtok = m0 + btl*48;
            int bg = gtok/3072, t = (gtok%3072)/48;
            const float* sp = extra + ((size_t)(bg*256 + n0 + c)*64 + t)*48;
            float* tr = Tt + c*100 + btl*48;
            #pragma unroll
            for (int j = 0; j < 12; j++){
                float4 s4 = *(const float4*)(sp + j*4);
                float4 t4 = *(float4*)(tr + j*4);
                t4.x += s4.x; t4.y += s4.y; t4.z += s4.z; t4.w += s4.w;
                *(float4*)(tr + j*4) = t4;
            }
        }
        __syncthreads();
        for (int it = 0; it < 12; it++){
            int idx = it*256 + tid;
            int cq = idx/96, nl = idx%96;
            float4 o;
            o.x = Tt[(cq*4+0)*100 + nl];
            o.y = Tt[(cq*4+1)*100 + nl];
            o.z = Tt[(cq*4+2)*100 + nl];
            o.w = Tt[(cq*4+3)*100 + nl];
            *(float4*)(outF + (size_t)(m0+nl)*256 + n0 + cq*4) = o;
        }
    }
    if constexpr (EPI == 3){
        float* Tt = (float*)smem;  // [128][100]
        #pragma unroll
        for (int nf = 0; nf < NF; nf++){
            int cl = wn*(BN/2) + nf*16 + l15;
            float bb = bias[n0 + cl];
            #pragma unroll
            for (int mf = 0; mf < 3; mf++){
                int tl = wm*48 + mf*16 + lq*4;
                f32x4 v = acc[mf][nf];
                #pragma unroll
                for (int r = 0; r < 4; r++){
                    float resid = extra[(size_t)(m0+tl+r)*256 + n0 + cl];
                    Tt[cl*100 + tl + r] = v[r] + bb + resid;
                }
            }
        }
        __syncthreads();
        {
            int btl = tid >> 7, c = tid & 127;
            int gtok = m0 + btl*48;
            int bg = gtok/3072, t = (gtok%3072)/48;
            float* dst = outF + ((size_t)(bg*256 + n0 + c)*64 + t)*48;
            const float* tr = Tt + c*100 + btl*48;
            #pragma unroll
            for (int j = 0; j < 12; j++)
                *(float4*)(dst + j*4) = *(const float4*)(tr + j*4);
        }
    }
}

// ---------------- K=64 MFMA GEMM: BM=96, BN=192, 4 waves (2x2: 48r x 96c) ----------------
template<int EPI>
__global__ __launch_bounds__(256) void gemm_k64(
    const unsigned short* __restrict__ A, int arb,
    const unsigned short* __restrict__ BT,
    const float* __restrict__ bias,
    unsigned short* __restrict__ out){
    __shared__ __align__(16) char smem[96*128 + 192*128];
    char* ldsA = smem;
    char* ldsB = smem + 96*128;
    int tid = threadIdx.x, lane = tid & 63;
    int wid = tid >> 6, wm = wid >> 1, wn = wid & 1;
    int l15 = lane & 15, lq = lane >> 4;
    int m0 = blockIdx.x * 96;

    stage_swz((const char*)A + (size_t)m0*arb, arb, ldsA, 96*8, tid);
    stage_swz((const char*)BT, 128, ldsB, 192*8, tid);
    __syncthreads();

    f32x4 acc[3][6];
    #pragma unroll
    for (int i = 0; i < 3; i++)
        #pragma unroll
        for (int j = 0; j < 6; j++){ f32x4 z = {0.f,0.f,0.f,0.f}; acc[i][j] = z; }

    #pragma unroll
    for (int ks = 0; ks < 2; ks++){
        bf16x8 a[3], b[6];
        int kb = ks*64 + lq*16;
        #pragma unroll
        for (int mf = 0; mf < 3; mf++) a[mf] = frag_ld(ldsA, wm*48 + mf*16 + l15, kb);
        #pragma unroll
        for (int nf = 0; nf < 6; nf++) b[nf] = frag_ld(ldsB, wn*96 + nf*16 + l15, kb);
        #pragma unroll
        for (int mf = 0; mf < 3; mf++)
            #pragma unroll
            for (int nf = 0; nf < 6; nf++)
                acc[mf][nf] = __builtin_amdgcn_mfma_f32_16x16x32_bf16(a[mf], b[nf], acc[mf][nf], 0, 0, 0);
    }

    size_t row0;
    if constexpr (EPI == 0) row0 = (size_t)m0;
    else {
        int b = m0/3072;
        row0 = (size_t)b*PROWS + 192 + (m0 - b*3072);
    }
    #pragma unroll
    for (int nf = 0; nf < 6; nf++){
        int col = wn*96 + nf*16 + l15;
        float bb = bias[col];
        #pragma unroll
        for (int mf = 0; mf < 3; mf++){
            size_t rr = row0 + wm*48 + mf*16 + lq*4;
            f32x4 v = acc[mf][nf];
            #pragma unroll
            for (int r = 0; r < 4; r++)
                out[(rr+r)*192 + col] = f2bf(v[r] + bb);
        }
    }
}

// ---------------- windowed attention: per (window, branch), fp32 softmax ----------------
__global__ __launch_bounds__(192) void attn_win(
        const unsigned short* __restrict__ qkvbuf,   // [2][Nt][192]
        unsigned short* __restrict__ attnout){       // [2][Nt][64]
    int win = blockIdx.x, br = blockIdx.y;
    size_t base = (size_t)br*NTOK + (size_t)win*48;
    __shared__ float Q[48*196];
    int tid = threadIdx.x;
    const unsigned short* src = qkvbuf + base*192;
    for (int i = 0; i < 6; i++){
        int ch = i*192 + tid;        // 1152 chunks of 8
        int v = ch/24, c8 = ch%24;
        uint4 u = *(const uint4*)(src + (size_t)v*192 + c8*8);
        unpk8(u, &Q[v*196 + c8*8]);
    }
    __syncthreads();
    int u = tid & 15, gh = tid >> 4, g = gh >> 2, h = gh & 3;
    int ru = g*16 + u;
    float qreg[16];
    #pragma unroll
    for (int d = 0; d < 16; d++) qreg[d] = Q[ru*196 + h*16 + d];
    float sc[16]; float mx = -1e30f;
    #pragma unroll
    for (int w = 0; w < 16; w++){
        float s = 0.f;
        #pragma unroll
        for (int d = 0; d < 16; d++) s += qreg[d]*Q[(g*16+w)*196 + 64 + h*16 + d];
        s *= 0.5f; sc[w] = s; mx = fmaxf(mx, s);
    }
    float sum = 0.f;
    #pragma unroll
    for (int w = 0; w < 16; w++){ sc[w] = expf(sc[w]-mx); sum += sc[w]; }
    float inv = 1.0f/sum;
    unsigned int w32[8];
    #pragma unroll
    for (int dp = 0; dp < 8; dp++){
        float o0 = 0.f, o1 = 0.f;
        #pragma unroll
        for (int w = 0; w < 16; w++){
            float p = sc[w];
            o0 += p*Q[(g*16+w)*196 + 128 + h*16 + dp*2];
            o1 += p*Q[(g*16+w)*196 + 128 + h*16 + dp*2+1];
        }
        w32[dp] = (unsigned int)f2bf(o0*inv) | ((unsigned int)f2bf(o1*inv) << 16);
    }
    unsigned short* dst = attnout + (base + ru)*64 + h*16;
    uint4 q0; q0.x=w32[0]; q0.y=w32[1]; q0.z=w32[2]; q0.w=w32[3];
    uint4 q1; q1.x=w32[4]; q1.y=w32[5]; q1.z=w32[6]; q1.w=w32[7];
    *(uint4*)(dst)   = q0;
    *(uint4*)(dst+8) = q1;
}

// ---------------- tcl as MFMA GEMM: K=960 via 5 shifted taps, BM=192, BN=64 ----------------
__global__ __launch_bounds__(256) void tcl_mfma(const unsigned short* __restrict__ A0p,
        const unsigned short* __restrict__ BT, const float* __restrict__ tb,
        unsigned short* __restrict__ ybf, int outoff){
    __shared__ __align__(16) char smem[192*128 + 64*128];
    char* ldsA = smem;
    char* ldsB = smem + 192*128;
    int tid = threadIdx.x, lane = tid & 63;
    int wid = tid >> 6;
    int l15 = lane & 15, lq = lane >> 4;
    int m0 = blockIdx.x * 192;
    int b = m0 / 3072;
    long brow0 = (long)b*PROWS + 192 + (m0 - b*3072);

    f32x4 acc[3][4];
    #pragma unroll
    for (int i = 0; i < 3; i++)
        #pragma unroll
        for (int j = 0; j < 4; j++){ f32x4 z = {0.f,0.f,0.f,0.f}; acc[i][j] = z; }

    for (int kh = 0; kh < 5; kh++){
        long rowA = brow0 + (long)(kh-4)*48;
        for (int kc3 = 0; kc3 < 3; kc3++){
            int kt = kh*3 + kc3;
            const char* As = (const char*)A0p + rowA*384 + kc3*128;
            const char* Bs = (const char*)BT + kt*128;
            stage_swz(As, 384, ldsA, 192*8, tid);
            stage_swz(Bs, 1920, ldsB, 64*8, tid);
            __syncthreads();
            #pragma unroll
            for (int ks = 0; ks < 2; ks++){
                bf16x8 a[3], bb[4];
                int kb = ks*64 + lq*16;
                #pragma unroll
                for (int mf = 0; mf < 3; mf++) a[mf] = frag_ld(ldsA, wid*48 + mf*16 + l15, kb);
                #pragma unroll
                for (int nf = 0; nf < 4; nf++) bb[nf] = frag_ld(ldsB, nf*16 + l15, kb);
                #pragma unroll
                for (int mf = 0; mf < 3; mf++)
                    #pragma unroll
                    for (int nf = 0; nf < 4; nf++)
                        acc[mf][nf] = __builtin_amdgcn_mfma_f32_16x16x32_bf16(a[mf], bb[nf], acc[mf][nf], 0, 0, 0);
            }
            __syncthreads();
        }
    }
    #pragma unroll
    for (int nf = 0; nf < 4; nf++){
        int col = nf*16 + l15;
        float bb = tb[col];
        #pragma unroll
        for (int mf = 0; mf < 3; mf++){
            int tok = m0 + wid*48 + mf*16 + lq*4;
            f32x4 v = acc[mf][nf];
            #pragma unroll
            for (int r = 0; r < 4; r++)
                ybf[(size_t)(tok+r)*256 + outoff + col] = f2bf(v[r] + bb);
        }
    }
}

// ---------------- y0: grouped V-mix -> ybf cols 0..63 (bf16 in/out) ----------------
__global__ __launch_bounds__(256) void y0_kernel(const unsigned short* __restrict__ fbf,
        const float* __restrict__ gct, unsigned short* __restrict__ ybf){
    int bt = blockIdx.x; int nb = bt*VV;
    __shared__ float X[48*68];
    for (int it = 0; it < 2; it++){
        int idx = it*256 + threadIdx.x;    // 384 = 48 x 8 chunks
        if (idx < 384){
            int v = idx >> 3, c8 = idx & 7;
            uint4 u = *(const uint4*)(fbf + (size_t)(nb+v)*256 + c8*8);
            unpk8(u, &X[v*68 + c8*8]);
        }
    }
    __syncthreads();
    int c = threadIdx.x % 64, vv = threadIdx.x / 64;
    int g = c >> 3;
    float acc[12] = {};
    for (int u = 0; u < 48; u++){
        float xv = X[u*68 + c];
        const float* gr = gct + (size_t)(g*48+u)*48 + vv*12;
        float4 g0 = *(const float4*)(gr);
        float4 g1 = *(const float4*)(gr+4);
        float4 g2 = *(const float4*)(gr+8);
        acc[0]+=xv*g0.x; acc[1]+=xv*g0.y; acc[2]+=xv*g0.z;  acc[3]+=xv*g0.w;
        acc[4]+=xv*g1.x; acc[5]+=xv*g1.y; acc[6]+=xv*g1.z;  acc[7]+=xv*g1.w;
        acc[8]+=xv*g2.x; acc[9]+=xv*g2.y; acc[10]+=xv*g2.z; acc[11]+=xv*g2.w;
    }
    #pragma unroll
    for (int j = 0; j < 12; j++)
        ybf[(size_t)(nb + vv*12 + j)*256 + c] = f2bf(acc[j]);
}

// ---------------- y1: grouped temporal conv (k=7) -> ybf cols 64..127 ----------------
__global__ __launch_bounds__(256) void y1_kernel(const unsigned short* __restrict__ fbf,
        const float* __restrict__ tw, const float* __restrict__ tb, unsigned short* __restrict__ ybf){
    int bt = blockIdx.x; int b = bt/TT, t = bt%TT;
    int o = threadIdx.x % 64, vv = threadIdx.x / 64;
    int g = o >> 3;
    float bv = tb[o];
    float acc[12];
    #pragma unroll
    for (int j = 0; j < 12; j++) acc[j] = bv;
    for (int kh = 0; kh < 7; kh++){
        int tt = t + kh - 3;
        if (tt < 0 || tt >= TT) continue;
        float wk[8];
        #pragma unroll
        for (int ci = 0; ci < 8; ci++) wk[ci] = tw[(o*8+ci)*7 + kh];
        int nb2 = (b*TT+tt)*VV;
        #pragma unroll
        for (int j = 0; j < 12; j++){
            uint4 u = *(const uint4*)(fbf + (size_t)(nb2 + vv*12 + j)*256 + 64 + g*8);
            float fv[8]; unpk8(u, fv);
            acc[j] += fv[0]*wk[0]+fv[1]*wk[1]+fv[2]*wk[2]+fv[3]*wk[3]
                    + fv[4]*wk[4]+fv[5]*wk[5]+fv[6]*wk[6]+fv[7]*wk[7];
        }
    }
    int nb = bt*VV;
    #pragma unroll
    for (int j = 0; j < 12; j++)
        ybf[(size_t)(nb + vv*12 + j)*256 + 64 + o] = f2bf(acc[j]);
}

// ---------------- LN2 fused: outt -> xn bf16 ----------------
__global__ __launch_bounds__(256) void ln2xn(const float* __restrict__ outt,
        const float* __restrict__ g, const float* __restrict__ bb, unsigned short* __restrict__ xn){
    int n = blockIdx.x*4 + (threadIdx.x >> 6);
    int lane = threadIdx.x & 63;
    const float* row = outt + (size_t)n*256;
    float4 v = *(const float4*)(row + lane*4);
    float s = v.x+v.y+v.z+v.w;
    float ss = v.x*v.x+v.y*v.y+v.z*v.z+v.w*v.w;
    for (int off = 32; off; off >>= 1){ s += __shfl_xor(s, off); ss += __shfl_xor(ss, off); }
    float m = s*(1.0f/256), rs = rsqrtf(ss*(1.0f/256) - m*m + LNE);
    float4 g4 = *(const float4*)(g + lane*4);
    float4 b4 = *(const float4*)(bb + lane*4);
    ushort4 u;
    u.x = f2bf((v.x-m)*rs*g4.x + b4.x);
    u.y = f2bf((v.y-m)*rs*g4.y + b4.y);
    u.z = f2bf((v.z-m)*rs*g4.z + b4.z);
    u.w = f2bf((v.w-m)*rs*g4.w + b4.w);
    *(ushort4*)(xn + (size_t)n*256 + lane*4) = u;
}

extern "C" void kernel_launch(void* const* d_in, const int* in_sizes, int n_in,
                              void* d_out, int out_size, void* d_ws, size_t ws_size,
                              hipStream_t stream){
    const float* input   = (const float*)d_in[0];
    const float* n1g     = (const float*)d_in[1];
    const float* n1b     = (const float*)d_in[2];
    const float* map_w   = (const float*)d_in[3];
    const float* map_b   = (const float*)d_in[4];
    const float* gconv   = (const float*)d_in[5];
    const float* tconv_w = (const float*)d_in[6];
    const float* tconv_b = (const float*)d_in[7];
    const float* qkv_w0  = (const float*)d_in[8];
    const float* qkv_b0  = (const float*)d_in[9];
    const float* aproj_w0= (const float*)d_in[10];
    const float* aproj_b0= (const float*)d_in[11];
    const float* tcl_w0  = (const float*)d_in[12];
    const float* tcl_b0  = (const float*)d_in[13];
    const float* qkv_w1  = (const float*)d_in[14];
    const float* qkv_b1  = (const float*)d_in[15];
    const float* aproj_w1= (const float*)d_in[16];
    const float* aproj_b1= (const float*)d_in[17];
    const float* tcl_w1  = (const float*)d_in[18];
    const float* tcl_b1  = (const float*)d_in[19];
    const float* proj_w  = (const float*)d_in[20];
    const float* proj_b  = (const float*)d_in[21];
    const float* n2g     = (const float*)d_in[22];
    const float* n2b     = (const float*)d_in[23];
    const float* mlp_w1  = (const float*)d_in[24];
    const float* mlp_b1  = (const float*)d_in[25];
    const float* mlp_w2  = (const float*)d_in[26];
    const float* mlp_b2  = (const float*)d_in[27];

    const size_t Nt = NTOK;
    if (ws_size < 354050048ull) return;

    char* base = (char*)d_ws;
    float* outt            = (float*)base;                           // 100,663,296
    unsigned short* fbf    = (unsigned short*)(base + 100663296);    //  50,331,648
    unsigned short* a0p    = (unsigned short*)(base + 150994944);    //  40,108,032
    unsigned short* qkvbuf = (unsigned short*)(base + 191102976);    //  75,497,472
    unsigned short* attnout= (unsigned short*)(base + 266600448);    //  25,165,824
    // pad 291,766,272 .. 301,989,888 (h overflow)
    unsigned short* A1     = (unsigned short*)(base + 301989888);    //  50,331,648
    char* wp = base + 352321536;
    float* gct            = (float*)wp;                 // 73,728
    unsigned short* mapT  = (unsigned short*)(wp + 73728);
    unsigned short* projT = mapT + 65536;
    unsigned short* w1T   = projT + 65536;
    unsigned short* w2T   = w1T + 262144;
    unsigned short* tclT0 = w2T + 262144;
    unsigned short* tclT1 = tclT0 + 61440;
    unsigned short* qkvT  = tclT1 + 61440;      // 2 x 12288
    unsigned short* aprojT= qkvT + 24576;       // 2 x 12288

    unsigned short* h   = fbf;                   // bf16 Nt x 1024: fbf..pad end (exact)
    unsigned short* xn  = A1;
    unsigned short* ybf = (unsigned short*)d_out;
    float* dout = (float*)d_out;

    prep_weights<<<256, 256, 0, stream>>>(gconv, tcl_w0, tcl_w1, map_w, proj_w, mlp_w1, mlp_w2,
                                          qkv_w0, qkv_w1, aproj_w0, aproj_w1,
                                          gct, mapT, projT, w1T, w2T, tclT0, tclT1, qkvT, aprojT);
    xpose_ln1<<<NB*TT, 256, 0, stream>>>(input, n1g, n1b, A1);
    mfma_gemm<256,4,128><<<2048, 256, 0, stream>>>(A1, mapT, map_b, nullptr, nullptr, fbf, 256, 2);
    hipMemsetAsync(a0p, 0, A0P_USH*sizeof(unsigned short), stream);
    gemm_k64<0><<<1024, 256, 0, stream>>>(fbf + 128, 512, qkvT,         qkv_b0, qkvbuf);
    gemm_k64<0><<<1024, 256, 0, stream>>>(fbf + 192, 512, qkvT + 12288, qkv_b1, qkvbuf + (size_t)Nt*192);
    attn_win<<<dim3(2048,2), 192, 0, stream>>>(qkvbuf, attnout);
    y0_kernel<<<NB*TT, 256, 0, stream>>>(fbf, gct, ybf);
    y1_kernel<<<NB*TT, 256, 0, stream>>>(fbf, tconv_w, tconv_b, ybf);
    gemm_k64<1><<<1024, 256, 0, stream>>>(attnout,                 128, aprojT,         aproj_b0, a0p);
    tcl_mfma<<<NTOK/192, 256, 0, stream>>>(a0p, tclT0, tcl_b0, ybf, 128);
    gemm_k64<1><<<1024, 256, 0, stream>>>(attnout + (size_t)Nt*64, 128, aprojT + 12288, aproj_b1, a0p);
    tcl_mfma<<<NTOK/192, 256, 0, stream>>>(a0p, tclT1, tcl_b1, ybf, 192);
    mfma_gemm<256,1,128><<<2048, 256, 0, stream>>>(ybf, projT, proj_b, input, outt, nullptr, 256, 2);
    ln2xn<<<NTOK/4, 256, 0, stream>>>(outt, n2g, n2b, xn);
    mfma_gemm<256,2,256><<<4096, 256, 0, stream>>>(xn, w1T, mlp_b1, nullptr, nullptr, h, 1024, 4);
    mfma_gemm<1024,3,128><<<2048, 256, 0, stream>>>(h, w2T, mlp_b2, outt, dout, nullptr, 256, 2);
}